// Round 6
// baseline (2867.526 us; speedup 1.0000x reference)
//
#include <hip/hip_runtime.h>
#include <hip/hip_bf16.h>

#define N_USERS 100000
#define N_ITEMS 50000
#define N_NODES 150000
#define DIM 64
#define N_EDGES 4000000
#define BATCH 4096

#define NBKT 768
#define BW 196           // nodes per bucket; 768*196 = 150528 >= 150000 (buckets 766-767 empty)
#define STRIDE 6912      // tmp records per bucket; mean 5208, sigma 74 -> +23 sigma
#define CAP 9            // LDS staging slots per bin in partition
#define PA_EDGES 3072    // edges per partition block (mean 4 per bin, P(>9) ~ 0.8%)
#define SCAP 256         // sampled-edge staging slots per partition block
#define SLIST_CAP 262144

// ---------------- bf16 helpers ----------------
__device__ __forceinline__ float blo(unsigned int u) { return __uint_as_float(u << 16); }
__device__ __forceinline__ float bhi(unsigned int u) { return __uint_as_float(u & 0xffff0000u); }
__device__ __forceinline__ unsigned int f2b(float f) {  // RTNE
    unsigned int x = __float_as_uint(f);
    return (x + 0x7fffu + ((x >> 16) & 1u)) >> 16;
}
__device__ __forceinline__ unsigned int pack2(float a, float b) {
    return f2b(a) | (f2b(b) << 16);
}

// fp32 tables -> bf16 concat table
__global__ void k_cvt(const float* __restrict__ uemb, const float* __restrict__ iemb,
                      ushort* __restrict__ out) {
    int i = (blockIdx.x * blockDim.x + threadIdx.x) * 4;
    if (i >= N_NODES * DIM) return;
    const float* srcp = (i < N_USERS * DIM) ? (uemb + i) : (iemb + (i - N_USERS * DIM));
    float4 v;
    v.x = __builtin_nontemporal_load(srcp + 0);
    v.y = __builtin_nontemporal_load(srcp + 1);
    v.z = __builtin_nontemporal_load(srcp + 2);
    v.w = __builtin_nontemporal_load(srcp + 3);
    *(uint2*)(out + i) = make_uint2(pack2(v.x, v.y), pack2(v.z, v.w));
}

// init: zero counters, mark sampled nodes in map (map pre-memset to -1)
__global__ void k_mark(const int* __restrict__ users, const int* __restrict__ items,
                       int* __restrict__ map, int* __restrict__ sdeg, int* __restrict__ sfill,
                       int* __restrict__ gcur, int* __restrict__ scnt) {
    int t = blockIdx.x * blockDim.x + threadIdx.x;
    if (t >= 2 * BATCH) return;
    sdeg[t] = 0;
    sfill[t] = 0;
    if (t < NBKT) gcur[t] = 0;
    if (t == 0) scnt[0] = 0;
    if (t < BATCH) map[users[t]] = t;                       // dup race: any winner is canonical
    else map[items[t - BATCH] + N_USERS] = t;               // t = BATCH + b
}

// ---------------- partition into fixed-stride buckets + sampled-edge filter ----------------
__global__ void __launch_bounds__(256) k_partition(
        const int* __restrict__ src, const int* __restrict__ dst,
        const float* __restrict__ vals, const int* __restrict__ map,
        int* __restrict__ gcur, int2* __restrict__ tmp,
        int* __restrict__ sdeg, int* __restrict__ scnt,
        unsigned long long* __restrict__ slist) {
    __shared__ int cnt[NBKT];                  // then reused as per-bin global base
    __shared__ int2 buf[NBKT][CAP];            // 55.3 KB
    __shared__ int pfx[NBKT + 1];
    __shared__ int wsum[4];
    __shared__ unsigned long long sbuf[SCAP];  // sampled-edge staging
    __shared__ int scnt_s, sbase_s;
    int t = threadIdx.x;
    for (int i = t; i < NBKT; i += 256) cnt[i] = 0;
    if (t == 0) scnt_s = 0;
    __syncthreads();
    size_t base = (size_t)blockIdx.x * PA_EDGES;
#pragma unroll
    for (int it = 0; it < PA_EDGES / 256; it++) {
        size_t i = base + (size_t)it * 256 + t;
        if (i < N_EDGES) {
            int d = __builtin_nontemporal_load(dst + i);
            int s = __builtin_nontemporal_load(src + i);
            float v = __builtin_nontemporal_load(vals + i);
            int b = d / BW;
            int local = d - b * BW;
            int2 rec = make_int2((s << 8) | local, __float_as_int(v));
            int slot = atomicAdd(&cnt[b], 1);
            if (slot < CAP) buf[b][slot] = rec;
            else tmp[(size_t)b * STRIDE + atomicAdd(&gcur[b], 1)] = rec;  // rare
            int ms = map[d];
            if (ms >= 0) {  // edge feeds a sampled node's layer-3 row
                atomicAdd(&sdeg[ms], 1);
                unsigned long long pk = ((unsigned long long)(unsigned int)__float_as_int(v) << 32) |
                                        ((unsigned int)ms << 18) | (unsigned int)s;
                int sl = atomicAdd(&scnt_s, 1);
                if (sl < SCAP) sbuf[sl] = pk;
                else slist[atomicAdd(scnt, 1)] = pk;  // very rare
            }
        }
    }
    __syncthreads();
    // drain sampled staging (coalesced)
    if (t == 0) {
        int c = min(scnt_s, SCAP);
        sbase_s = (c > 0) ? atomicAdd(scnt, c) : 0;
    }
    __syncthreads();
    int stot = min(scnt_s, SCAP);
    for (int i = t; i < stot; i += 256) slist[sbase_s + i] = sbuf[i];
    // drain bucket staging: per-bin base + LDS prefix + binary-search coalesced copy
    int c0 = 0, c1 = 0, c2 = 0;
    {
        int b0 = 3 * t, b1 = 3 * t + 1, b2 = 3 * t + 2;
        c0 = min(cnt[b0], CAP); c1 = min(cnt[b1], CAP); c2 = min(cnt[b2], CAP);
        int g0 = (c0 > 0) ? atomicAdd(&gcur[b0], c0) : 0;
        int g1 = (c1 > 0) ? atomicAdd(&gcur[b1], c1) : 0;
        int g2 = (c2 > 0) ? atomicAdd(&gcur[b2], c2) : 0;
        __syncthreads();
        cnt[b0] = g0; cnt[b1] = g1; cnt[b2] = g2;  // reuse cnt as gbase
    }
    int tsum = c0 + c1 + c2;
    int lane = t & 63, w = t >> 6;
    int incl = tsum;
    for (int o = 1; o < 64; o <<= 1) {
        int y = __shfl_up(incl, o);
        if (lane >= o) incl += y;
    }
    if (lane == 63) wsum[w] = incl;
    __syncthreads();
    int woff = 0;
    for (int j = 0; j < w; j++) woff += wsum[j];
    int excl = woff + incl - tsum;
    pfx[3 * t] = excl;
    pfx[3 * t + 1] = excl + c0;
    pfx[3 * t + 2] = excl + c0 + c1;
    if (t == 255) pfx[NBKT] = excl + tsum;
    __syncthreads();
    int total = pfx[NBKT];
    for (int f = t; f < total; f += 256) {
        int lo = 0, hi = NBKT - 1;
        while (lo < hi) {
            int mid = (lo + hi + 1) >> 1;
            if (pfx[mid] <= f) lo = mid; else hi = mid - 1;
        }
        int slot = f - pfx[lo];
        tmp[(size_t)lo * STRIDE + cnt[lo] + slot] = buf[lo][slot];
    }
}

// scan sdeg[8192] -> srow[8193]
__global__ void k_sscan(const int* __restrict__ sdeg, int* __restrict__ srow) {
    __shared__ int ws[16];
    int t = threadIdx.x;  // 1024
    int v[8], p = 0;
#pragma unroll
    for (int j = 0; j < 8; j++) { v[j] = sdeg[t * 8 + j]; p += v[j]; }
    int lane = t & 63, w = t >> 6;
    int incl = p;
    for (int o = 1; o < 64; o <<= 1) {
        int y = __shfl_up(incl, o);
        if (lane >= o) incl += y;
    }
    if (lane == 63) ws[w] = incl;
    __syncthreads();
    int woff = 0;
    for (int j = 0; j < w; j++) woff += ws[j];
    int run = woff + incl - p;
#pragma unroll
    for (int j = 0; j < 8; j++) { srow[t * 8 + j] = run; run += v[j]; }
    if (t == 1023) srow[8192] = run;
}

// scatter sampled edges into slot-grouped sfin
__global__ void k_sscatter(const unsigned long long* __restrict__ slist,
                           const int* __restrict__ scnt, const int* __restrict__ srow,
                           int* __restrict__ sfill, int2* __restrict__ sfin) {
    int i = blockIdx.x * blockDim.x + threadIdx.x;
    if (i >= scnt[0]) return;
    unsigned long long pk = slist[i];
    int s = (int)(pk & 0x3FFFFu);
    int slot = (int)((pk >> 18) & 8191u);
    int vbits = (int)(pk >> 32);
    int pos = srow[slot] + atomicAdd(&sfill[slot], 1);
    sfin[pos] = make_int2(s, vbits);
}

// ---------------- fused SpMM: one block per bucket, LDS fp32 accumulator ----------------
__global__ void __launch_bounds__(512) k_spmmf(
        const ushort* __restrict__ ein, ushort* __restrict__ eout,
        const int* __restrict__ gcur, const int2* __restrict__ tmp) {
    __shared__ float acc[BW * 65];  // +1 pad: bank = (local + 8q + j) & 31
    int b = blockIdx.x, t = threadIdx.x;  // 512 threads
    for (int i = t; i < BW * 65; i += 512) acc[i] = 0.f;
    __syncthreads();
    int count = gcur[b];
    const int2* tb = tmp + (size_t)b * STRIDE;
    int grp = t >> 3;  // 0..63
    int q = t & 7;     // dim-octet within row
    for (int e = grp; e < count; e += 64) {
        unsigned long long rv = __builtin_nontemporal_load((const unsigned long long*)&tb[e]);
        int rx = (int)(unsigned int)rv;
        float v = __uint_as_float((unsigned int)(rv >> 32));
        int s = ((unsigned int)rx) >> 8;
        int local = rx & 255;
        const uint4 u = *(const uint4*)(ein + (size_t)s * DIM + q * 8);
        float* arow = acc + local * 65 + q * 8;
        atomicAdd(arow + 0, v * blo(u.x));
        atomicAdd(arow + 1, v * bhi(u.x));
        atomicAdd(arow + 2, v * blo(u.y));
        atomicAdd(arow + 3, v * bhi(u.y));
        atomicAdd(arow + 4, v * blo(u.z));
        atomicAdd(arow + 5, v * bhi(u.z));
        atomicAdd(arow + 6, v * blo(u.w));
        atomicAdd(arow + 7, v * bhi(u.w));
    }
    __syncthreads();
    // write out bf16, coalesced
    int node0 = b * BW;
    int nodes = min(BW, max(0, N_NODES - node0));
    unsigned int* outw = (unsigned int*)(eout + (size_t)node0 * DIM);
    for (int f = t; f < nodes * 32; f += 512) {  // one uint = 2 bf16
        int r = f >> 5, dp = f & 31;
        float a0 = acc[r * 65 + dp * 2];
        float a1 = acc[r * 65 + dp * 2 + 1];
        outw[r * 32 + dp] = pack2(a0, a1);
    }
}

// layer-3 at sampled slots only -> l3 (overwrite; zero rows for empty slots)
__global__ void k_samp(const ushort* __restrict__ ein, const int* __restrict__ srow,
                       const int2* __restrict__ sfin, float* __restrict__ l3) {
    int slot = (blockIdx.x * blockDim.x + threadIdx.x) >> 6;
    if (slot >= 2 * BATCH) return;
    int lane = threadIdx.x & 63;
    int g = lane >> 3;
    int q = lane & 7;
    int start = srow[slot], end = srow[slot + 1];
    float acc[8];
#pragma unroll
    for (int j = 0; j < 8; j++) acc[j] = 0.f;
    for (int e = start + g; e < end; e += 8) {
        int2 r = sfin[e];
        const uint4 u = *(const uint4*)(ein + (size_t)r.x * DIM + q * 8);
        float v = __int_as_float(r.y);
        acc[0] += v * blo(u.x); acc[1] += v * bhi(u.x);
        acc[2] += v * blo(u.y); acc[3] += v * bhi(u.y);
        acc[4] += v * blo(u.z); acc[5] += v * bhi(u.z);
        acc[6] += v * blo(u.w); acc[7] += v * bhi(u.w);
    }
#pragma unroll
    for (int off = 8; off < 64; off <<= 1) {
#pragma unroll
        for (int j = 0; j < 8; j++) acc[j] += __shfl_xor(acc[j], off);
    }
    if (lane < 8) {
        float* row = l3 + (size_t)slot * DIM + q * 8;
        *(float4*)row = make_float4(acc[0], acc[1], acc[2], acc[3]);
        *(float4*)(row + 4) = make_float4(acc[4], acc[5], acc[6], acc[7]);
    }
}

// layer-0: overwrite both acc buffers from fp32 input tables
__global__ void k_gather0(const float* __restrict__ uemb, const float* __restrict__ iemb,
                          const int* __restrict__ users, const int* __restrict__ items,
                          float* __restrict__ accU, float* __restrict__ accI) {
    int i = blockIdx.x * blockDim.x + threadIdx.x;
    if (i >= 2 * BATCH * DIM) return;
    int j = (i < BATCH * DIM) ? i : i - BATCH * DIM;
    int b = j >> 6, l = j & 63;
    if (i < BATCH * DIM) accU[j] = uemb[(size_t)users[b] * DIM + l];
    else accI[j] = iemb[(size_t)items[b] * DIM + l];
}

// layers 1-2: accumulate both sample sets from bf16 table
__global__ void k_gacc(const ushort* __restrict__ emb, const int* __restrict__ users,
                       const int* __restrict__ items, float* __restrict__ accU,
                       float* __restrict__ accI) {
    int i = blockIdx.x * blockDim.x + threadIdx.x;
    if (i >= 2 * BATCH * DIM) return;
    int j = (i < BATCH * DIM) ? i : i - BATCH * DIM;
    int b = j >> 6, l = j & 63;
    if (i < BATCH * DIM) {
        unsigned int u = emb[(size_t)users[b] * DIM + l];
        accU[j] += __uint_as_float(u << 16);
    } else {
        unsigned int u = emb[(size_t)(items[b] + N_USERS) * DIM + l];
        accI[j] += __uint_as_float(u << 16);
    }
}

// final dot: (acc + l3[canonical slot]) pairs
__global__ void k_dot(const float* __restrict__ accU, const float* __restrict__ accI,
                      const float* __restrict__ l3, const int* __restrict__ map,
                      const int* __restrict__ users, const int* __restrict__ items,
                      float* __restrict__ out) {
    int b = (blockIdx.x * blockDim.x + threadIdx.x) >> 6;
    if (b >= BATCH) return;
    int lane = threadIdx.x & 63;
    int cu = map[users[b]];
    int ci = map[items[b] + N_USERS];
    float aU = accU[b * 64 + lane] + l3[(size_t)cu * 64 + lane];
    float aI = accI[b * 64 + lane] + l3[(size_t)ci * 64 + lane];
    float p = aU * aI;
    for (int off = 32; off; off >>= 1) p += __shfl_xor(p, off);
    if (lane == 0) out[b] = p * (1.0f / 16.0f);  // (acc/4)·(acc/4)
}

// ---------------- launch ----------------

extern "C" void kernel_launch(void* const* d_in, const int* in_sizes, int n_in,
                              void* d_out, int out_size, void* d_ws, size_t ws_size,
                              hipStream_t stream) {
    const float* user_emb = (const float*)d_in[0];
    const float* item_emb = (const float*)d_in[1];
    const float* vals = (const float*)d_in[2];
    const int* src = (const int*)d_in[3];
    const int* dst = (const int*)d_in[4];
    const int* users = (const int*)d_in[5];
    const int* items = (const int*)d_in[6];
    float* out = (float*)d_out;

    char* ws = (char*)d_ws;
    size_t off = 0;
    auto alloc = [&](size_t bytes) {
        char* p = ws + off;
        off += (bytes + 255) & ~(size_t)255;
        return p;
    };
    ushort* ebf0 = (ushort*)alloc((size_t)N_NODES * DIM * 2);       // 19.2 MB
    ushort* ebf1 = (ushort*)alloc((size_t)N_NODES * DIM * 2);       // 19.2 MB
    ushort* ebf2 = (ushort*)alloc((size_t)N_NODES * DIM * 2);       // 19.2 MB
    int2* tmp = (int2*)alloc((size_t)NBKT * STRIDE * 8);            // 42.5 MB
    int* map = (int*)alloc((size_t)N_NODES * 4);                    // 0.6 MB
    int* gcur = (int*)alloc((size_t)NBKT * 4);
    int* sdeg = (int*)alloc((size_t)2 * BATCH * 4);
    int* srow = (int*)alloc((size_t)(2 * BATCH + 1) * 4);
    int* sfill = (int*)alloc((size_t)2 * BATCH * 4);
    int* scnt = (int*)alloc(256);
    unsigned long long* slist = (unsigned long long*)alloc((size_t)SLIST_CAP * 8);  // 2 MB
    int2* sfin = (int2*)alloc((size_t)SLIST_CAP * 8);               // 2 MB
    float* l3 = (float*)alloc((size_t)2 * BATCH * DIM * 4);         // 2 MB
    float* accU = (float*)alloc((size_t)BATCH * DIM * 4);
    float* accI = (float*)alloc((size_t)BATCH * DIM * 4);

    hipMemsetAsync(map, 0xFF, (size_t)N_NODES * 4, stream);  // map = -1

    k_mark<<<(2 * BATCH + 255) / 256, 256, 0, stream>>>(users, items, map, sdeg, sfill, gcur, scnt);
    k_cvt<<<(N_NODES * DIM / 4 + 255) / 256, 256, 0, stream>>>(user_emb, item_emb, ebf0);

    int pa_blocks = (N_EDGES + PA_EDGES - 1) / PA_EDGES;
    k_partition<<<pa_blocks, 256, 0, stream>>>(src, dst, vals, map, gcur, tmp, sdeg, scnt, slist);
    k_sscan<<<1, 1024, 0, stream>>>(sdeg, srow);
    k_sscatter<<<SLIST_CAP / 256, 256, 0, stream>>>(slist, scnt, srow, sfill, sfin);

    int gb = (2 * BATCH * DIM + 255) / 256;
    k_gather0<<<gb, 256, 0, stream>>>(user_emb, item_emb, users, items, accU, accI);

    // layer 1: ebf0 -> ebf1
    k_spmmf<<<NBKT, 512, 0, stream>>>(ebf0, ebf1, gcur, tmp);
    k_gacc<<<gb, 256, 0, stream>>>(ebf1, users, items, accU, accI);
    // layer 2: ebf1 -> ebf2
    k_spmmf<<<NBKT, 512, 0, stream>>>(ebf1, ebf2, gcur, tmp);
    k_gacc<<<gb, 256, 0, stream>>>(ebf2, users, items, accU, accI);
    // layer 3: sampled rows only -> l3
    k_samp<<<(2 * BATCH * 64 + 255) / 256, 256, 0, stream>>>(ebf2, srow, sfin, l3);

    k_dot<<<(BATCH * 64 + 255) / 256, 256, 0, stream>>>(accU, accI, l3, map, users, items, out);
}

// Round 7
// 479.294 us; speedup vs baseline: 5.9828x; 5.9828x over previous
//
#include <hip/hip_runtime.h>
#include <hip/hip_bf16.h>

#define N_USERS 100000
#define N_ITEMS 50000
#define N_NODES 150000
#define DIM 64
#define N_EDGES 4000000
#define BATCH 4096

#define NBKT 256
#define BW 587           // nodes per bucket; 256*587 = 150272 >= 150000
#define STRIDE 18432     // tmp records per bucket (mean 15625, sigma ~125 -> +22 sigma)
#define CAP 24           // LDS staging slots per bin in partition
#define PA_EDGES 4096    // edges per partition block
#define SCAP 384         // sampled-edge staging slots per partition block (mean ~217)
#define SLIST_CAP 262144

// ---------------- bf16 helpers ----------------
__device__ __forceinline__ float blo(unsigned int u) { return __uint_as_float(u << 16); }
__device__ __forceinline__ float bhi(unsigned int u) { return __uint_as_float(u & 0xffff0000u); }
__device__ __forceinline__ unsigned int f2b(float f) {  // RTNE
    unsigned int x = __float_as_uint(f);
    return (x + 0x7fffu + ((x >> 16) & 1u)) >> 16;
}
__device__ __forceinline__ unsigned int pack2(float a, float b) {
    return f2b(a) | (f2b(b) << 16);
}
__device__ __forceinline__ int2 nt_load_int2(const int2* p) {
    unsigned long long v = __builtin_nontemporal_load((const unsigned long long*)p);
    return make_int2((int)(unsigned int)v, (int)(v >> 32));
}

// fp32 tables -> bf16 concat table
__global__ void k_cvt(const float* __restrict__ uemb, const float* __restrict__ iemb,
                      ushort* __restrict__ out) {
    int i = (blockIdx.x * blockDim.x + threadIdx.x) * 4;
    if (i >= N_NODES * DIM) return;
    const float* srcp = (i < N_USERS * DIM) ? (uemb + i) : (iemb + (i - N_USERS * DIM));
    float4 v;
    v.x = __builtin_nontemporal_load(srcp + 0);
    v.y = __builtin_nontemporal_load(srcp + 1);
    v.z = __builtin_nontemporal_load(srcp + 2);
    v.w = __builtin_nontemporal_load(srcp + 3);
    *(uint2*)(out + i) = make_uint2(pack2(v.x, v.y), pack2(v.z, v.w));
}

// init: zero counters, mark sampled nodes in map (map pre-memset to -1)
__global__ void k_mark(const int* __restrict__ users, const int* __restrict__ items,
                       int* __restrict__ map, int* __restrict__ sdeg, int* __restrict__ sfill,
                       int* __restrict__ gcur, int* __restrict__ scnt) {
    int t = blockIdx.x * blockDim.x + threadIdx.x;
    if (t >= 2 * BATCH) return;
    sdeg[t] = 0;
    sfill[t] = 0;
    if (t < NBKT) gcur[t] = 0;
    if (t == 0) scnt[0] = 0;
    if (t < BATCH) map[users[t]] = t;          // dup race: any winner is canonical
    else map[items[t - BATCH] + N_USERS] = t;  // t = BATCH + b
}

// ---------------- partition into fixed-stride buckets + sampled-edge filter ----------------
__global__ void __launch_bounds__(256) k_partition(
        const int* __restrict__ src, const int* __restrict__ dst,
        const float* __restrict__ vals, const int* __restrict__ map,
        int* __restrict__ gcur, int2* __restrict__ tmp,
        int* __restrict__ sdeg, int* __restrict__ scnt,
        unsigned long long* __restrict__ slist) {
    __shared__ int cnt[NBKT];                  // then reused: gbase_s holds global bases
    __shared__ int2 buf[NBKT][CAP];            // 48 KB
    __shared__ int gbase_s[NBKT];
    __shared__ int pfx[NBKT + 1];
    __shared__ int wsum[4];
    __shared__ unsigned long long sbuf[SCAP];  // sampled-edge staging
    __shared__ int scnt_s, sbase_s;
    int t = threadIdx.x;
    cnt[t] = 0;
    if (t == 0) scnt_s = 0;
    __syncthreads();
    size_t base = (size_t)blockIdx.x * PA_EDGES;
#pragma unroll
    for (int it = 0; it < PA_EDGES / 256; it++) {
        size_t i = base + (size_t)it * 256 + t;
        if (i < N_EDGES) {
            int d = __builtin_nontemporal_load(dst + i);
            int s = __builtin_nontemporal_load(src + i);
            float v = __builtin_nontemporal_load(vals + i);
            int b = d / BW;
            int local = d - b * BW;
            int2 rec = make_int2((s << 10) | local, __float_as_int(v));
            int slot = atomicAdd(&cnt[b], 1);
            if (slot < CAP) buf[b][slot] = rec;
            else tmp[(size_t)b * STRIDE + atomicAdd(&gcur[b], 1)] = rec;  // ~2% path
            int ms = map[d];
            if (ms >= 0) {  // edge feeds a sampled node's layer-3 row
                atomicAdd(&sdeg[ms], 1);
                unsigned long long pk = ((unsigned long long)(unsigned int)__float_as_int(v) << 32) |
                                        ((unsigned int)ms << 18) | (unsigned int)s;
                int sl = atomicAdd(&scnt_s, 1);
                if (sl < SCAP) sbuf[sl] = pk;
                else slist[atomicAdd(scnt, 1)] = pk;  // very rare
            }
        }
    }
    __syncthreads();
    // drain sampled staging (coalesced)
    if (t == 0) {
        int c = min(scnt_s, SCAP);
        sbase_s = (c > 0) ? atomicAdd(scnt, c) : 0;
    }
    __syncthreads();
    int stot = min(scnt_s, SCAP);
    for (int i = t; i < stot; i += 256) slist[sbase_s + i] = sbuf[i];
    // drain bucket staging: per-bin base + LDS prefix + binary-search coalesced copy
    int c = min(cnt[t], CAP);
    int p = (c > 0) ? atomicAdd(&gcur[t], c) : 0;
    gbase_s[t] = p;
    int lane = t & 63, w = t >> 6;
    int incl = c;
    for (int o = 1; o < 64; o <<= 1) {
        int y = __shfl_up(incl, o);
        if (lane >= o) incl += y;
    }
    if (lane == 63) wsum[w] = incl;
    __syncthreads();
    int woff = 0;
    for (int j = 0; j < w; j++) woff += wsum[j];
    int excl = woff + incl - c;
    pfx[t] = excl;
    if (t == 255) pfx[NBKT] = excl + c;
    __syncthreads();
    int total = pfx[NBKT];
    for (int f = t; f < total; f += 256) {
        int lo = 0, hi = NBKT - 1;
        while (lo < hi) {  // largest bin with pfx[bin] <= f
            int mid = (lo + hi + 1) >> 1;
            if (pfx[mid] <= f) lo = mid; else hi = mid - 1;
        }
        int slot = f - pfx[lo];
        tmp[(size_t)lo * STRIDE + gbase_s[lo] + slot] = buf[lo][slot];
    }
}

// scan 256 bucket sizes (in gcur) -> bucket_ptr[257] (dense fin layout)
__global__ void k_bscan(const int* __restrict__ gcur, int* __restrict__ bucket_ptr) {
    int lane = threadIdx.x;  // 64 threads
    int carry = 0;
    for (int c = 0; c < 4; c++) {
        int i = c * 64 + lane;
        int x = gcur[i];
        int incl = x;
        for (int off = 1; off < 64; off <<= 1) {
            int y = __shfl_up(incl, off);
            if (lane >= off) incl += y;
        }
        bucket_ptr[i] = carry + incl - x;
        carry += __shfl(incl, 63);
    }
    if (lane == 0) bucket_ptr[NBKT] = N_EDGES;
}

// scan sdeg[8192] -> srow[8193]
__global__ void k_sscan(const int* __restrict__ sdeg, int* __restrict__ srow) {
    __shared__ int ws[16];
    int t = threadIdx.x;  // 1024
    int v[8], p = 0;
#pragma unroll
    for (int j = 0; j < 8; j++) { v[j] = sdeg[t * 8 + j]; p += v[j]; }
    int lane = t & 63, w = t >> 6;
    int incl = p;
    for (int o = 1; o < 64; o <<= 1) {
        int y = __shfl_up(incl, o);
        if (lane >= o) incl += y;
    }
    if (lane == 63) ws[w] = incl;
    __syncthreads();
    int woff = 0;
    for (int j = 0; j < w; j++) woff += ws[j];
    int run = woff + incl - p;
#pragma unroll
    for (int j = 0; j < 8; j++) { srow[t * 8 + j] = run; run += v[j]; }
    if (t == 1023) srow[8192] = run;
}

// scatter sampled edges into slot-grouped sfin
__global__ void k_sscatter(const unsigned long long* __restrict__ slist,
                           const int* __restrict__ scnt, const int* __restrict__ srow,
                           int* __restrict__ sfill, int2* __restrict__ sfin) {
    int i = blockIdx.x * blockDim.x + threadIdx.x;
    if (i >= scnt[0]) return;
    unsigned long long pk = slist[i];
    int s = (int)(pk & 0x3FFFFu);
    int slot = (int)((pk >> 18) & 8191u);
    int vbits = (int)(pk >> 32);
    int pos = srow[slot] + atomicAdd(&sfill[slot], 1);
    sfin[pos] = make_int2(s, vbits);
}

// ---------------- pass B: sort within bucket (LDS hist + scan), emit dense CSR ----------------
__global__ void k_bsort(const int2* __restrict__ tmp, const int* __restrict__ gcur,
                        const int* __restrict__ bucket_ptr, int* __restrict__ row_ptr,
                        int2* __restrict__ fin) {
    __shared__ int cnt[BW + 64];
    __shared__ int off[BW + 64];
    int b = blockIdx.x, t = threadIdx.x;  // 512 threads
    int node0 = b * BW;
    int nodes = min(BW, N_NODES - node0);
    int gbase = bucket_ptr[b];
    int count = gcur[b];
    const int2* tb = tmp + (size_t)b * STRIDE;
    for (int i = t; i < BW + 64; i += 512) cnt[i] = 0;
    __syncthreads();
    for (int e = t; e < count; e += 512) atomicAdd(&cnt[nt_load_int2(&tb[e]).x & 1023], 1);
    __syncthreads();
    if (t < 64) {
        int lane = t;
        int carry = 0;
        for (int c = 0; c < 10; c++) {
            int i = c * 64 + lane;
            int x = (i < nodes) ? cnt[i] : 0;
            int incl = x;
            for (int o = 1; o < 64; o <<= 1) {
                int y = __shfl_up(incl, o);
                if (lane >= o) incl += y;
            }
            if (i <= nodes) off[i] = carry + incl - x;
            carry += __shfl(incl, 63);
        }
    }
    __syncthreads();
    for (int i = t; i <= nodes; i += 512)
        if (node0 + i <= N_NODES) row_ptr[node0 + i] = gbase + off[i];
    __syncthreads();
    for (int e = t; e < count; e += 512) {
        int2 r = nt_load_int2(&tb[e]);
        int local = r.x & 1023;
        int pos = gbase + atomicAdd(&off[local], 1);
        fin[pos] = make_int2(r.x >> 10, r.y);  // plain store: L2 write-combines 40KB region
    }
}

// ---------------- bf16 SpMM: one wave per dst node, 8 groups x 8 lanes ----------------
#define SPMM_EDGE(r)                                                              \
    {                                                                             \
        const uint4 u = *(const uint4*)(ein + (size_t)(r).x * DIM + q * 8);       \
        float v = __int_as_float((r).y);                                          \
        acc[0] += v * blo(u.x); acc[1] += v * bhi(u.x);                           \
        acc[2] += v * blo(u.y); acc[3] += v * bhi(u.y);                           \
        acc[4] += v * blo(u.z); acc[5] += v * bhi(u.z);                           \
        acc[6] += v * blo(u.w); acc[7] += v * bhi(u.w);                           \
    }

__global__ void k_spmm16(const ushort* __restrict__ ein, ushort* __restrict__ eout,
                         const int* __restrict__ row_ptr, const int2* __restrict__ fin) {
    int wave = (blockIdx.x * blockDim.x + threadIdx.x) >> 6;
    if (wave >= N_NODES) return;
    int lane = threadIdx.x & 63;
    int g = lane >> 3;  // edge group 0..7
    int q = lane & 7;   // 8 bf16 dims per lane
    int start = row_ptr[wave], end = row_ptr[wave + 1];
    float acc[8];
#pragma unroll
    for (int j = 0; j < 8; j++) acc[j] = 0.f;
    int e = start + g;
    for (; e + 8 < end; e += 16) {
        int2 r0 = nt_load_int2(&fin[e]);
        int2 r1 = nt_load_int2(&fin[e + 8]);
        SPMM_EDGE(r0);
        SPMM_EDGE(r1);
    }
    for (; e < end; e += 8) {
        int2 r0 = nt_load_int2(&fin[e]);
        SPMM_EDGE(r0);
    }
#pragma unroll
    for (int off = 8; off < 64; off <<= 1) {
#pragma unroll
        for (int j = 0; j < 8; j++) acc[j] += __shfl_xor(acc[j], off);
    }
    if (lane < 8) {
        // plain store: output is next layer's gather table, keep it in L2
        uint4 p;
        p.x = pack2(acc[0], acc[1]);
        p.y = pack2(acc[2], acc[3]);
        p.z = pack2(acc[4], acc[5]);
        p.w = pack2(acc[6], acc[7]);
        *(uint4*)(eout + (size_t)wave * DIM + q * 8) = p;
    }
}

// layer-3 at sampled slots only -> l3 (overwrite; zero rows for empty slots)
__global__ void k_samp(const ushort* __restrict__ ein, const int* __restrict__ srow,
                       const int2* __restrict__ sfin, float* __restrict__ l3) {
    int slot = (blockIdx.x * blockDim.x + threadIdx.x) >> 6;
    if (slot >= 2 * BATCH) return;
    int lane = threadIdx.x & 63;
    int g = lane >> 3;
    int q = lane & 7;
    int start = srow[slot], end = srow[slot + 1];
    float acc[8];
#pragma unroll
    for (int j = 0; j < 8; j++) acc[j] = 0.f;
    for (int e = start + g; e < end; e += 8) {
        int2 r = sfin[e];
        SPMM_EDGE(r);
    }
#pragma unroll
    for (int off = 8; off < 64; off <<= 1) {
#pragma unroll
        for (int j = 0; j < 8; j++) acc[j] += __shfl_xor(acc[j], off);
    }
    if (lane < 8) {
        float* row = l3 + (size_t)slot * DIM + q * 8;
        *(float4*)row = make_float4(acc[0], acc[1], acc[2], acc[3]);
        *(float4*)(row + 4) = make_float4(acc[4], acc[5], acc[6], acc[7]);
    }
}

// layer-0: overwrite both acc buffers from fp32 input tables
__global__ void k_gather0(const float* __restrict__ uemb, const float* __restrict__ iemb,
                          const int* __restrict__ users, const int* __restrict__ items,
                          float* __restrict__ accU, float* __restrict__ accI) {
    int i = blockIdx.x * blockDim.x + threadIdx.x;
    if (i >= 2 * BATCH * DIM) return;
    int j = (i < BATCH * DIM) ? i : i - BATCH * DIM;
    int b = j >> 6, l = j & 63;
    if (i < BATCH * DIM) accU[j] = uemb[(size_t)users[b] * DIM + l];
    else accI[j] = iemb[(size_t)items[b] * DIM + l];
}

// layers 1-2: accumulate both sample sets from bf16 table
__global__ void k_gacc(const ushort* __restrict__ emb, const int* __restrict__ users,
                       const int* __restrict__ items, float* __restrict__ accU,
                       float* __restrict__ accI) {
    int i = blockIdx.x * blockDim.x + threadIdx.x;
    if (i >= 2 * BATCH * DIM) return;
    int j = (i < BATCH * DIM) ? i : i - BATCH * DIM;
    int b = j >> 6, l = j & 63;
    if (i < BATCH * DIM) {
        unsigned int u = emb[(size_t)users[b] * DIM + l];
        accU[j] += __uint_as_float(u << 16);
    } else {
        unsigned int u = emb[(size_t)(items[b] + N_USERS) * DIM + l];
        accI[j] += __uint_as_float(u << 16);
    }
}

// final dot: (acc + l3[canonical slot]) pairs
__global__ void k_dot(const float* __restrict__ accU, const float* __restrict__ accI,
                      const float* __restrict__ l3, const int* __restrict__ map,
                      const int* __restrict__ users, const int* __restrict__ items,
                      float* __restrict__ out) {
    int b = (blockIdx.x * blockDim.x + threadIdx.x) >> 6;
    if (b >= BATCH) return;
    int lane = threadIdx.x & 63;
    int cu = map[users[b]];
    int ci = map[items[b] + N_USERS];
    float aU = accU[b * 64 + lane] + l3[(size_t)cu * 64 + lane];
    float aI = accI[b * 64 + lane] + l3[(size_t)ci * 64 + lane];
    float p = aU * aI;
    for (int off = 32; off; off >>= 1) p += __shfl_xor(p, off);
    if (lane == 0) out[b] = p * (1.0f / 16.0f);  // (acc/4)·(acc/4)
}

// ---------------- launch ----------------

extern "C" void kernel_launch(void* const* d_in, const int* in_sizes, int n_in,
                              void* d_out, int out_size, void* d_ws, size_t ws_size,
                              hipStream_t stream) {
    const float* user_emb = (const float*)d_in[0];
    const float* item_emb = (const float*)d_in[1];
    const float* vals = (const float*)d_in[2];
    const int* src = (const int*)d_in[3];
    const int* dst = (const int*)d_in[4];
    const int* users = (const int*)d_in[5];
    const int* items = (const int*)d_in[6];
    float* out = (float*)d_out;

    char* ws = (char*)d_ws;
    size_t off = 0;
    auto alloc = [&](size_t bytes) {
        char* p = ws + off;
        off += (bytes + 255) & ~(size_t)255;
        return p;
    };
    ushort* ebf0 = (ushort*)alloc((size_t)N_NODES * DIM * 2);  // 19.2 MB bf16 concat tables
    ushort* ebf1 = (ushort*)alloc((size_t)N_NODES * DIM * 2);  // layer-1 out (aliases tmp lo)
    ushort* ebf2 = (ushort*)alloc((size_t)N_NODES * DIM * 2);  // layer-2 out (aliases tmp hi)
    int2* fin = (int2*)alloc((size_t)N_EDGES * 8);             // 32 MB dense CSR records
    int* row_ptr = (int*)alloc((size_t)(N_NODES + 1) * 4);
    int* bucket_ptr = (int*)alloc((size_t)(NBKT + 1) * 4);
    int* gcur = (int*)alloc((size_t)NBKT * 4);
    int* map = (int*)alloc((size_t)N_NODES * 4);
    int* sdeg = (int*)alloc((size_t)2 * BATCH * 4);
    int* srow = (int*)alloc((size_t)(2 * BATCH + 1) * 4);
    int* sfill = (int*)alloc((size_t)2 * BATCH * 4);
    int* scnt = (int*)alloc(256);
    unsigned long long* slist = (unsigned long long*)alloc((size_t)SLIST_CAP * 8);
    int2* sfin = (int2*)alloc((size_t)SLIST_CAP * 8);
    float* l3 = (float*)alloc((size_t)2 * BATCH * DIM * 4);
    float* accU = (float*)alloc((size_t)BATCH * DIM * 4);
    float* accI = (float*)alloc((size_t)BATCH * DIM * 4);
    // 37.75 MB fixed-stride partition scratch aliases ebf1+ebf2 (38.4 MB contiguous);
    // tmp is dead after k_bsort, before ebf1/2 are first written.
    int2* tmp = (int2*)ebf1;

    hipMemsetAsync(map, 0xFF, (size_t)N_NODES * 4, stream);  // map = -1

    k_mark<<<(2 * BATCH + 255) / 256, 256, 0, stream>>>(users, items, map, sdeg, sfill, gcur, scnt);
    k_cvt<<<(N_NODES * DIM / 4 + 255) / 256, 256, 0, stream>>>(user_emb, item_emb, ebf0);

    int pa_blocks = (N_EDGES + PA_EDGES - 1) / PA_EDGES;
    k_partition<<<pa_blocks, 256, 0, stream>>>(src, dst, vals, map, gcur, tmp, sdeg, scnt, slist);
    k_bscan<<<1, 64, 0, stream>>>(gcur, bucket_ptr);
    k_sscan<<<1, 1024, 0, stream>>>(sdeg, srow);
    k_sscatter<<<SLIST_CAP / 256, 256, 0, stream>>>(slist, scnt, srow, sfill, sfin);
    k_bsort<<<NBKT, 512, 0, stream>>>(tmp, gcur, bucket_ptr, row_ptr, fin);

    int gb = (2 * BATCH * DIM + 255) / 256;
    k_gather0<<<gb, 256, 0, stream>>>(user_emb, item_emb, users, items, accU, accI);

    int spmm_blocks = (N_NODES * 64 + 255) / 256;
    // layer 1: ebf0 -> ebf1
    k_spmm16<<<spmm_blocks, 256, 0, stream>>>(ebf0, ebf1, row_ptr, fin);
    k_gacc<<<gb, 256, 0, stream>>>(ebf1, users, items, accU, accI);
    // layer 2: ebf1 -> ebf2
    k_spmm16<<<spmm_blocks, 256, 0, stream>>>(ebf1, ebf2, row_ptr, fin);
    k_gacc<<<gb, 256, 0, stream>>>(ebf2, users, items, accU, accI);
    // layer 3: sampled rows only -> l3
    k_samp<<<(2 * BATCH * 64 + 255) / 256, 256, 0, stream>>>(ebf2, srow, sfin, l3);

    k_dot<<<(BATCH * 64 + 255) / 256, 256, 0, stream>>>(accU, accI, l3, map, users, items, out);
}

// Round 8
// 475.305 us; speedup vs baseline: 6.0330x; 1.0084x over previous
//
#include <hip/hip_runtime.h>
#include <hip/hip_bf16.h>

#define N_USERS 100000
#define N_ITEMS 50000
#define N_NODES 150000
#define DIM 64
#define N_EDGES 4000000
#define BATCH 4096

#define NBKT 256
#define BW 587           // nodes per bucket; 256*587 = 150272 >= 150000
#define STRIDE 18432     // tmp records per bucket (mean 15625, sigma ~125 -> +22 sigma)
#define CAP 24           // LDS staging slots per bin in partition
#define PA_EDGES 4096    // edges per partition block
#define SCAP 384         // sampled-edge staging slots per partition block (mean ~217)
#define SLIST_CAP 262144

// ---------------- bf16 helpers ----------------
__device__ __forceinline__ float blo(unsigned int u) { return __uint_as_float(u << 16); }
__device__ __forceinline__ float bhi(unsigned int u) { return __uint_as_float(u & 0xffff0000u); }
__device__ __forceinline__ unsigned int f2b(float f) {  // RTNE
    unsigned int x = __float_as_uint(f);
    return (x + 0x7fffu + ((x >> 16) & 1u)) >> 16;
}
__device__ __forceinline__ unsigned int pack2(float a, float b) {
    return f2b(a) | (f2b(b) << 16);
}
__device__ __forceinline__ int2 nt_load_int2(const int2* p) {
    unsigned long long v = __builtin_nontemporal_load((const unsigned long long*)p);
    return make_int2((int)(unsigned int)v, (int)(v >> 32));
}

// fp32 tables -> bf16 concat table, fused with sampled-node marking + counter init
__global__ void k_markcvt(const float* __restrict__ uemb, const float* __restrict__ iemb,
                          ushort* __restrict__ out, const int* __restrict__ users,
                          const int* __restrict__ items, int* __restrict__ map,
                          int* __restrict__ sdeg, int* __restrict__ sfill,
                          int* __restrict__ gcur, int* __restrict__ scnt) {
    int tid = blockIdx.x * blockDim.x + threadIdx.x;
    if (tid < 2 * BATCH) {
        sdeg[tid] = 0;
        sfill[tid] = 0;
        if (tid < NBKT) gcur[tid] = 0;
        if (tid == 0) scnt[0] = 0;
        if (tid < BATCH) map[users[tid]] = tid;          // dup race: any winner is canonical
        else map[items[tid - BATCH] + N_USERS] = tid;    // tid = BATCH + b
    }
    int i = tid * 4;
    if (i >= N_NODES * DIM) return;
    const float* srcp = (i < N_USERS * DIM) ? (uemb + i) : (iemb + (i - N_USERS * DIM));
    float4 v;
    v.x = __builtin_nontemporal_load(srcp + 0);
    v.y = __builtin_nontemporal_load(srcp + 1);
    v.z = __builtin_nontemporal_load(srcp + 2);
    v.w = __builtin_nontemporal_load(srcp + 3);
    *(uint2*)(out + i) = make_uint2(pack2(v.x, v.y), pack2(v.z, v.w));
}

// ---------------- partition into fixed-stride buckets + sampled-edge filter ----------------
__global__ void __launch_bounds__(256) k_partition(
        const int* __restrict__ src, const int* __restrict__ dst,
        const float* __restrict__ vals, const int* __restrict__ map,
        int* __restrict__ gcur, int2* __restrict__ tmp,
        int* __restrict__ sdeg, int* __restrict__ scnt,
        unsigned long long* __restrict__ slist) {
    __shared__ int cnt[NBKT];
    __shared__ int2 buf[NBKT][CAP];            // 48 KB
    __shared__ int gbase_s[NBKT];
    __shared__ int pfx[NBKT + 1];
    __shared__ int wsum[4];
    __shared__ unsigned long long sbuf[SCAP];  // sampled-edge staging
    __shared__ int scnt_s, sbase_s;
    int t = threadIdx.x;
    cnt[t] = 0;
    if (t == 0) scnt_s = 0;
    __syncthreads();
    size_t base = (size_t)blockIdx.x * PA_EDGES;
#pragma unroll
    for (int it = 0; it < PA_EDGES / 256; it++) {
        size_t i = base + (size_t)it * 256 + t;
        if (i < N_EDGES) {
            int d = __builtin_nontemporal_load(dst + i);
            int s = __builtin_nontemporal_load(src + i);
            float v = __builtin_nontemporal_load(vals + i);
            int b = d / BW;
            int local = d - b * BW;
            int2 rec = make_int2((s << 10) | local, __float_as_int(v));
            int slot = atomicAdd(&cnt[b], 1);
            if (slot < CAP) buf[b][slot] = rec;
            else tmp[(size_t)b * STRIDE + atomicAdd(&gcur[b], 1)] = rec;  // ~2% path
            int ms = map[d];
            if (ms >= 0) {  // edge feeds a sampled node's layer-3 row
                atomicAdd(&sdeg[ms], 1);
                unsigned long long pk = ((unsigned long long)(unsigned int)__float_as_int(v) << 32) |
                                        ((unsigned int)ms << 18) | (unsigned int)s;
                int sl = atomicAdd(&scnt_s, 1);
                if (sl < SCAP) sbuf[sl] = pk;
                else slist[atomicAdd(scnt, 1)] = pk;  // very rare
            }
        }
    }
    __syncthreads();
    // drain sampled staging (coalesced)
    if (t == 0) {
        int c = min(scnt_s, SCAP);
        sbase_s = (c > 0) ? atomicAdd(scnt, c) : 0;
    }
    __syncthreads();
    int stot = min(scnt_s, SCAP);
    for (int i = t; i < stot; i += 256) slist[sbase_s + i] = sbuf[i];
    // drain bucket staging: per-bin base + LDS prefix + binary-search coalesced copy
    int c = min(cnt[t], CAP);
    int p = (c > 0) ? atomicAdd(&gcur[t], c) : 0;
    gbase_s[t] = p;
    int lane = t & 63, w = t >> 6;
    int incl = c;
    for (int o = 1; o < 64; o <<= 1) {
        int y = __shfl_up(incl, o);
        if (lane >= o) incl += y;
    }
    if (lane == 63) wsum[w] = incl;
    __syncthreads();
    int woff = 0;
    for (int j = 0; j < w; j++) woff += wsum[j];
    int excl = woff + incl - c;
    pfx[t] = excl;
    if (t == 255) pfx[NBKT] = excl + c;
    __syncthreads();
    int total = pfx[NBKT];
    for (int f = t; f < total; f += 256) {
        int lo = 0, hi = NBKT - 1;
        while (lo < hi) {  // largest bin with pfx[bin] <= f
            int mid = (lo + hi + 1) >> 1;
            if (pfx[mid] <= f) lo = mid; else hi = mid - 1;
        }
        int slot = f - pfx[lo];
        tmp[(size_t)lo * STRIDE + gbase_s[lo] + slot] = buf[lo][slot];
    }
}

// fused scans: block 0 = bucket scan (gcur -> bucket_ptr), block 1 = sampled scan (sdeg -> srow)
__global__ void k_scan2(const int* __restrict__ gcur, int* __restrict__ bucket_ptr,
                        const int* __restrict__ sdeg, int* __restrict__ srow) {
    __shared__ int ws[16];
    int t = threadIdx.x;  // 1024
    if (blockIdx.x == 0) {
        if (t >= 64) return;
        int lane = t;
        int carry = 0;
        for (int c = 0; c < 4; c++) {
            int i = c * 64 + lane;
            int x = gcur[i];
            int incl = x;
            for (int off = 1; off < 64; off <<= 1) {
                int y = __shfl_up(incl, off);
                if (lane >= off) incl += y;
            }
            bucket_ptr[i] = carry + incl - x;
            carry += __shfl(incl, 63);
        }
        if (lane == 0) bucket_ptr[NBKT] = N_EDGES;
        return;
    }
    int v[8], p = 0;
#pragma unroll
    for (int j = 0; j < 8; j++) { v[j] = sdeg[t * 8 + j]; p += v[j]; }
    int lane = t & 63, w = t >> 6;
    int incl = p;
    for (int o = 1; o < 64; o <<= 1) {
        int y = __shfl_up(incl, o);
        if (lane >= o) incl += y;
    }
    if (lane == 63) ws[w] = incl;
    __syncthreads();
    int woff = 0;
    for (int j = 0; j < w; j++) woff += ws[j];
    int run = woff + incl - p;
#pragma unroll
    for (int j = 0; j < 8; j++) { srow[t * 8 + j] = run; run += v[j]; }
    if (t == 1023) srow[8192] = run;
}

// scatter sampled edges into slot-grouped sfin
__global__ void k_sscatter(const unsigned long long* __restrict__ slist,
                           const int* __restrict__ scnt, const int* __restrict__ srow,
                           int* __restrict__ sfill, int2* __restrict__ sfin) {
    int i = blockIdx.x * blockDim.x + threadIdx.x;
    if (i >= scnt[0]) return;
    unsigned long long pk = slist[i];
    int s = (int)(pk & 0x3FFFFu);
    int slot = (int)((pk >> 18) & 8191u);
    int vbits = (int)(pk >> 32);
    int pos = srow[slot] + atomicAdd(&sfill[slot], 1);
    sfin[pos] = make_int2(s, vbits);
}

// ---------------- pass B: sort within bucket (LDS hist + scan), emit dense CSR ----------------
__global__ void k_bsort(const int2* __restrict__ tmp, const int* __restrict__ gcur,
                        const int* __restrict__ bucket_ptr, int* __restrict__ row_ptr,
                        int2* __restrict__ fin) {
    __shared__ int cnt[BW + 64];
    __shared__ int off[BW + 64];
    int b = blockIdx.x, t = threadIdx.x;  // 512 threads
    int node0 = b * BW;
    int nodes = min(BW, N_NODES - node0);
    int gbase = bucket_ptr[b];
    int count = gcur[b];
    const int2* tb = tmp + (size_t)b * STRIDE;
    for (int i = t; i < BW + 64; i += 512) cnt[i] = 0;
    __syncthreads();
    for (int e = t; e < count; e += 512) atomicAdd(&cnt[nt_load_int2(&tb[e]).x & 1023], 1);
    __syncthreads();
    if (t < 64) {
        int lane = t;
        int carry = 0;
        for (int c = 0; c < 10; c++) {
            int i = c * 64 + lane;
            int x = (i < nodes) ? cnt[i] : 0;
            int incl = x;
            for (int o = 1; o < 64; o <<= 1) {
                int y = __shfl_up(incl, o);
                if (lane >= o) incl += y;
            }
            if (i <= nodes) off[i] = carry + incl - x;
            carry += __shfl(incl, 63);
        }
    }
    __syncthreads();
    for (int i = t; i <= nodes; i += 512)
        if (node0 + i <= N_NODES) row_ptr[node0 + i] = gbase + off[i];
    __syncthreads();
    for (int e = t; e < count; e += 512) {
        int2 r = nt_load_int2(&tb[e]);
        int local = r.x & 1023;
        int pos = gbase + atomicAdd(&off[local], 1);
        fin[pos] = make_int2(r.x >> 10, r.y);  // plain store: L2 write-combines 40KB region
    }
}

// ---------------- bf16 SpMM: one wave per dst node, 8 groups x 8 lanes ----------------
#define SPMM_EDGE(r)                                                              \
    {                                                                             \
        const uint4 u = *(const uint4*)(ein + (size_t)(r).x * DIM + q * 8);       \
        float v = __int_as_float((r).y);                                          \
        acc[0] += v * blo(u.x); acc[1] += v * bhi(u.x);                           \
        acc[2] += v * blo(u.y); acc[3] += v * bhi(u.y);                           \
        acc[4] += v * blo(u.z); acc[5] += v * bhi(u.z);                           \
        acc[6] += v * blo(u.w); acc[7] += v * bhi(u.w);                           \
    }

__global__ void k_spmm16(const ushort* __restrict__ ein, ushort* __restrict__ eout,
                         const int* __restrict__ row_ptr, const int2* __restrict__ fin) {
    int wave = (blockIdx.x * blockDim.x + threadIdx.x) >> 6;
    if (wave >= N_NODES) return;
    int lane = threadIdx.x & 63;
    int g = lane >> 3;  // edge group 0..7
    int q = lane & 7;   // 8 bf16 dims per lane
    int start = row_ptr[wave], end = row_ptr[wave + 1];
    float acc[8];
#pragma unroll
    for (int j = 0; j < 8; j++) acc[j] = 0.f;
    int e = start + g;
    for (; e + 8 < end; e += 16) {
        int2 r0 = nt_load_int2(&fin[e]);
        int2 r1 = nt_load_int2(&fin[e + 8]);
        SPMM_EDGE(r0);
        SPMM_EDGE(r1);
    }
    for (; e < end; e += 8) {
        int2 r0 = nt_load_int2(&fin[e]);
        SPMM_EDGE(r0);
    }
#pragma unroll
    for (int off = 8; off < 64; off <<= 1) {
#pragma unroll
        for (int j = 0; j < 8; j++) acc[j] += __shfl_xor(acc[j], off);
    }
    if (lane < 8) {
        // NT store: output reuse is served from L3 anyway; keep L2 free for the gather table
        unsigned long long lo = (unsigned long long)pack2(acc[0], acc[1]) |
                                ((unsigned long long)pack2(acc[2], acc[3]) << 32);
        unsigned long long hi = (unsigned long long)pack2(acc[4], acc[5]) |
                                ((unsigned long long)pack2(acc[6], acc[7]) << 32);
        unsigned long long* op = (unsigned long long*)(eout + (size_t)wave * DIM + q * 8);
        __builtin_nontemporal_store(lo, op);
        __builtin_nontemporal_store(hi, op + 1);
    }
}

// layer-3 at sampled slots only -> l3 (overwrite; zero rows for empty slots)
__global__ void k_samp(const ushort* __restrict__ ein, const int* __restrict__ srow,
                       const int2* __restrict__ sfin, float* __restrict__ l3) {
    int slot = (blockIdx.x * blockDim.x + threadIdx.x) >> 6;
    if (slot >= 2 * BATCH) return;
    int lane = threadIdx.x & 63;
    int g = lane >> 3;
    int q = lane & 7;
    int start = srow[slot], end = srow[slot + 1];
    float acc[8];
#pragma unroll
    for (int j = 0; j < 8; j++) acc[j] = 0.f;
    for (int e = start + g; e < end; e += 8) {
        int2 r = sfin[e];
        SPMM_EDGE(r);
    }
#pragma unroll
    for (int off = 8; off < 64; off <<= 1) {
#pragma unroll
        for (int j = 0; j < 8; j++) acc[j] += __shfl_xor(acc[j], off);
    }
    if (lane < 8) {
        float* row = l3 + (size_t)slot * DIM + q * 8;
        *(float4*)row = make_float4(acc[0], acc[1], acc[2], acc[3]);
        *(float4*)(row + 4) = make_float4(acc[4], acc[5], acc[6], acc[7]);
    }
}

// layer-0 + layer-1: acc = fp32 table row + bf16 ebf1 row (fused, overwrite)
__global__ void k_gacc0(const float* __restrict__ uemb, const float* __restrict__ iemb,
                        const ushort* __restrict__ emb, const int* __restrict__ users,
                        const int* __restrict__ items, float* __restrict__ accU,
                        float* __restrict__ accI) {
    int i = blockIdx.x * blockDim.x + threadIdx.x;
    if (i >= 2 * BATCH * DIM) return;
    int j = (i < BATCH * DIM) ? i : i - BATCH * DIM;
    int b = j >> 6, l = j & 63;
    if (i < BATCH * DIM) {
        int n = users[b];
        unsigned int u = emb[(size_t)n * DIM + l];
        accU[j] = uemb[(size_t)n * DIM + l] + __uint_as_float(u << 16);
    } else {
        int n = items[b];
        unsigned int u = emb[(size_t)(n + N_USERS) * DIM + l];
        accI[j] = iemb[(size_t)n * DIM + l] + __uint_as_float(u << 16);
    }
}

// layer-2: accumulate both sample sets from bf16 table
__global__ void k_gacc(const ushort* __restrict__ emb, const int* __restrict__ users,
                       const int* __restrict__ items, float* __restrict__ accU,
                       float* __restrict__ accI) {
    int i = blockIdx.x * blockDim.x + threadIdx.x;
    if (i >= 2 * BATCH * DIM) return;
    int j = (i < BATCH * DIM) ? i : i - BATCH * DIM;
    int b = j >> 6, l = j & 63;
    if (i < BATCH * DIM) {
        unsigned int u = emb[(size_t)users[b] * DIM + l];
        accU[j] += __uint_as_float(u << 16);
    } else {
        unsigned int u = emb[(size_t)(items[b] + N_USERS) * DIM + l];
        accI[j] += __uint_as_float(u << 16);
    }
}

// final dot: (acc + l3[canonical slot]) pairs
__global__ void k_dot(const float* __restrict__ accU, const float* __restrict__ accI,
                      const float* __restrict__ l3, const int* __restrict__ map,
                      const int* __restrict__ users, const int* __restrict__ items,
                      float* __restrict__ out) {
    int b = (blockIdx.x * blockDim.x + threadIdx.x) >> 6;
    if (b >= BATCH) return;
    int lane = threadIdx.x & 63;
    int cu = map[users[b]];
    int ci = map[items[b] + N_USERS];
    float aU = accU[b * 64 + lane] + l3[(size_t)cu * 64 + lane];
    float aI = accI[b * 64 + lane] + l3[(size_t)ci * 64 + lane];
    float p = aU * aI;
    for (int off = 32; off; off >>= 1) p += __shfl_xor(p, off);
    if (lane == 0) out[b] = p * (1.0f / 16.0f);  // (acc/4)·(acc/4)
}

// ---------------- launch ----------------

extern "C" void kernel_launch(void* const* d_in, const int* in_sizes, int n_in,
                              void* d_out, int out_size, void* d_ws, size_t ws_size,
                              hipStream_t stream) {
    const float* user_emb = (const float*)d_in[0];
    const float* item_emb = (const float*)d_in[1];
    const float* vals = (const float*)d_in[2];
    const int* src = (const int*)d_in[3];
    const int* dst = (const int*)d_in[4];
    const int* users = (const int*)d_in[5];
    const int* items = (const int*)d_in[6];
    float* out = (float*)d_out;

    char* ws = (char*)d_ws;
    size_t off = 0;
    auto alloc = [&](size_t bytes) {
        char* p = ws + off;
        off += (bytes + 255) & ~(size_t)255;
        return p;
    };
    ushort* ebf0 = (ushort*)alloc((size_t)N_NODES * DIM * 2);  // 19.2 MB bf16 concat tables
    ushort* ebf1 = (ushort*)alloc((size_t)N_NODES * DIM * 2);  // layer-1 out (aliases tmp lo)
    ushort* ebf2 = (ushort*)alloc((size_t)N_NODES * DIM * 2);  // layer-2 out (aliases tmp hi)
    int2* fin = (int2*)alloc((size_t)N_EDGES * 8);             // 32 MB dense CSR records
    int* row_ptr = (int*)alloc((size_t)(N_NODES + 1) * 4);
    int* bucket_ptr = (int*)alloc((size_t)(NBKT + 1) * 4);
    int* gcur = (int*)alloc((size_t)NBKT * 4);
    int* map = (int*)alloc((size_t)N_NODES * 4);
    int* sdeg = (int*)alloc((size_t)2 * BATCH * 4);
    int* srow = (int*)alloc((size_t)(2 * BATCH + 1) * 4);
    int* sfill = (int*)alloc((size_t)2 * BATCH * 4);
    int* scnt = (int*)alloc(256);
    unsigned long long* slist = (unsigned long long*)alloc((size_t)SLIST_CAP * 8);
    int2* sfin = (int2*)alloc((size_t)SLIST_CAP * 8);
    float* l3 = (float*)alloc((size_t)2 * BATCH * DIM * 4);
    float* accU = (float*)alloc((size_t)BATCH * DIM * 4);
    float* accI = (float*)alloc((size_t)BATCH * DIM * 4);
    // 37.75 MB fixed-stride partition scratch aliases ebf1+ebf2 (38.4 MB contiguous);
    // tmp is dead after k_bsort, before ebf1/2 are first written.
    int2* tmp = (int2*)ebf1;

    hipMemsetAsync(map, 0xFF, (size_t)N_NODES * 4, stream);  // map = -1

    k_markcvt<<<(N_NODES * DIM / 4 + 255) / 256, 256, 0, stream>>>(
        user_emb, item_emb, ebf0, users, items, map, sdeg, sfill, gcur, scnt);

    int pa_blocks = (N_EDGES + PA_EDGES - 1) / PA_EDGES;
    k_partition<<<pa_blocks, 256, 0, stream>>>(src, dst, vals, map, gcur, tmp, sdeg, scnt, slist);
    k_scan2<<<2, 1024, 0, stream>>>(gcur, bucket_ptr, sdeg, srow);
    k_sscatter<<<SLIST_CAP / 256, 256, 0, stream>>>(slist, scnt, srow, sfill, sfin);
    k_bsort<<<NBKT, 512, 0, stream>>>(tmp, gcur, bucket_ptr, row_ptr, fin);

    int gb = (2 * BATCH * DIM + 255) / 256;
    int spmm_blocks = (N_NODES * 64 + 255) / 256;
    // layer 1: ebf0 -> ebf1, then fused layer-0 + layer-1 sampled accumulate
    k_spmm16<<<spmm_blocks, 256, 0, stream>>>(ebf0, ebf1, row_ptr, fin);
    k_gacc0<<<gb, 256, 0, stream>>>(user_emb, item_emb, ebf1, users, items, accU, accI);
    // layer 2: ebf1 -> ebf2
    k_spmm16<<<spmm_blocks, 256, 0, stream>>>(ebf1, ebf2, row_ptr, fin);
    k_gacc<<<gb, 256, 0, stream>>>(ebf2, users, items, accU, accI);
    // layer 3: sampled rows only -> l3
    k_samp<<<(2 * BATCH * 64 + 255) / 256, 256, 0, stream>>>(ebf2, srow, sfin, l3);

    k_dot<<<(BATCH * 64 + 255) / 256, 256, 0, stream>>>(accU, accI, l3, map, users, items, out);
}

// Round 9
// 420.856 us; speedup vs baseline: 6.8136x; 1.1294x over previous
//
#include <hip/hip_runtime.h>
#include <hip/hip_bf16.h>

#define N_USERS 100000
#define N_ITEMS 50000
#define N_NODES 150000
#define DIM 64
#define N_EDGES 4000000
#define BATCH 4096

#define NBKT 256
#define BW 587           // nodes per bucket; 256*587 = 150272 >= 150000
#define STRIDE 18432     // tmp records per bucket (mean 15625, sigma ~125 -> +22 sigma)
#define CAP 24           // LDS staging slots per bin in partition
#define PA_EDGES 4096    // edges per partition block
#define SCAP 384         // sampled-edge staging slots per partition block (mean ~217)
#define SLIST_CAP 262144

// ---------------- bf16 helpers ----------------
__device__ __forceinline__ float blo(unsigned int u) { return __uint_as_float(u << 16); }
__device__ __forceinline__ float bhi(unsigned int u) { return __uint_as_float(u & 0xffff0000u); }
__device__ __forceinline__ unsigned int f2b(float f) {  // RTNE
    unsigned int x = __float_as_uint(f);
    return (x + 0x7fffu + ((x >> 16) & 1u)) >> 16;
}
__device__ __forceinline__ unsigned int pack2(float a, float b) {
    return f2b(a) | (f2b(b) << 16);
}

// fp32 tables -> bf16 concat table, fused with sampled-node marking + counter init
__global__ void k_markcvt(const float* __restrict__ uemb, const float* __restrict__ iemb,
                          ushort* __restrict__ out, const int* __restrict__ users,
                          const int* __restrict__ items, int* __restrict__ map,
                          int* __restrict__ sdeg, int* __restrict__ sfill,
                          int* __restrict__ gcur, int* __restrict__ scnt) {
    int tid = blockIdx.x * blockDim.x + threadIdx.x;
    if (tid < 2 * BATCH) {
        sdeg[tid] = 0;
        sfill[tid] = 0;
        if (tid < NBKT) gcur[tid] = 0;
        if (tid == 0) scnt[0] = 0;
        if (tid < BATCH) map[users[tid]] = tid;          // dup race: any winner is canonical
        else map[items[tid - BATCH] + N_USERS] = tid;    // tid = BATCH + b
    }
    int i = tid * 4;
    if (i >= N_NODES * DIM) return;
    const float* srcp = (i < N_USERS * DIM) ? (uemb + i) : (iemb + (i - N_USERS * DIM));
    float4 v;
    v.x = __builtin_nontemporal_load(srcp + 0);
    v.y = __builtin_nontemporal_load(srcp + 1);
    v.z = __builtin_nontemporal_load(srcp + 2);
    v.w = __builtin_nontemporal_load(srcp + 3);
    *(uint2*)(out + i) = make_uint2(pack2(v.x, v.y), pack2(v.z, v.w));
}

// ---------------- partition into fixed-stride buckets + sampled-edge filter ----------------
__global__ void __launch_bounds__(256) k_partition(
        const int* __restrict__ src, const int* __restrict__ dst,
        const float* __restrict__ vals, const int* __restrict__ map,
        int* __restrict__ gcur, int2* __restrict__ tmp,
        int* __restrict__ sdeg, int* __restrict__ scnt,
        unsigned long long* __restrict__ slist) {
    __shared__ int cnt[NBKT];
    __shared__ int2 buf[NBKT][CAP];            // 48 KB
    __shared__ int gbase_s[NBKT];
    __shared__ int pfx[NBKT + 1];
    __shared__ int wsum[4];
    __shared__ unsigned long long sbuf[SCAP];  // sampled-edge staging
    __shared__ int scnt_s, sbase_s;
    int t = threadIdx.x;
    cnt[t] = 0;
    if (t == 0) scnt_s = 0;
    __syncthreads();
    size_t base = (size_t)blockIdx.x * PA_EDGES;
#pragma unroll
    for (int it = 0; it < PA_EDGES / 256; it++) {
        size_t i = base + (size_t)it * 256 + t;
        if (i < N_EDGES) {
            int d = __builtin_nontemporal_load(dst + i);
            int s = __builtin_nontemporal_load(src + i);
            float v = __builtin_nontemporal_load(vals + i);
            int b = d / BW;
            int local = d - b * BW;
            int2 rec = make_int2((s << 10) | local, __float_as_int(v));
            int slot = atomicAdd(&cnt[b], 1);
            if (slot < CAP) buf[b][slot] = rec;
            else tmp[(size_t)b * STRIDE + atomicAdd(&gcur[b], 1)] = rec;  // ~2% path
            int ms = map[d];
            if (ms >= 0) {  // edge feeds a sampled node's layer-3 row
                atomicAdd(&sdeg[ms], 1);
                unsigned long long pk = ((unsigned long long)(unsigned int)__float_as_int(v) << 32) |
                                        ((unsigned int)ms << 18) | (unsigned int)s;
                int sl = atomicAdd(&scnt_s, 1);
                if (sl < SCAP) sbuf[sl] = pk;
                else slist[atomicAdd(scnt, 1)] = pk;  // very rare
            }
        }
    }
    __syncthreads();
    // drain sampled staging (coalesced)
    if (t == 0) {
        int c = min(scnt_s, SCAP);
        sbase_s = (c > 0) ? atomicAdd(scnt, c) : 0;
    }
    __syncthreads();
    int stot = min(scnt_s, SCAP);
    for (int i = t; i < stot; i += 256) slist[sbase_s + i] = sbuf[i];
    // drain bucket staging: per-bin base + LDS prefix + binary-search coalesced copy
    int c = min(cnt[t], CAP);
    int p = (c > 0) ? atomicAdd(&gcur[t], c) : 0;
    gbase_s[t] = p;
    int lane = t & 63, w = t >> 6;
    int incl = c;
    for (int o = 1; o < 64; o <<= 1) {
        int y = __shfl_up(incl, o);
        if (lane >= o) incl += y;
    }
    if (lane == 63) wsum[w] = incl;
    __syncthreads();
    int woff = 0;
    for (int j = 0; j < w; j++) woff += wsum[j];
    int excl = woff + incl - c;
    pfx[t] = excl;
    if (t == 255) pfx[NBKT] = excl + c;
    __syncthreads();
    int total = pfx[NBKT];
    for (int f = t; f < total; f += 256) {
        int lo = 0, hi = NBKT - 1;
        while (lo < hi) {  // largest bin with pfx[bin] <= f
            int mid = (lo + hi + 1) >> 1;
            if (pfx[mid] <= f) lo = mid; else hi = mid - 1;
        }
        int slot = f - pfx[lo];
        tmp[(size_t)lo * STRIDE + gbase_s[lo] + slot] = buf[lo][slot];
    }
}

// fused scans: block 0 = bucket scan (gcur -> bucket_ptr), block 1 = sampled scan (sdeg -> srow)
__global__ void k_scan2(const int* __restrict__ gcur, int* __restrict__ bucket_ptr,
                        const int* __restrict__ sdeg, int* __restrict__ srow) {
    __shared__ int ws[16];
    int t = threadIdx.x;  // 1024
    if (blockIdx.x == 0) {
        if (t >= 64) return;
        int lane = t;
        int carry = 0;
        for (int c = 0; c < 4; c++) {
            int i = c * 64 + lane;
            int x = gcur[i];
            int incl = x;
            for (int off = 1; off < 64; off <<= 1) {
                int y = __shfl_up(incl, off);
                if (lane >= off) incl += y;
            }
            bucket_ptr[i] = carry + incl - x;
            carry += __shfl(incl, 63);
        }
        if (lane == 0) bucket_ptr[NBKT] = N_EDGES;
        return;
    }
    int v[8], p = 0;
#pragma unroll
    for (int j = 0; j < 8; j++) { v[j] = sdeg[t * 8 + j]; p += v[j]; }
    int lane = t & 63, w = t >> 6;
    int incl = p;
    for (int o = 1; o < 64; o <<= 1) {
        int y = __shfl_up(incl, o);
        if (lane >= o) incl += y;
    }
    if (lane == 63) ws[w] = incl;
    __syncthreads();
    int woff = 0;
    for (int j = 0; j < w; j++) woff += ws[j];
    int run = woff + incl - p;
#pragma unroll
    for (int j = 0; j < 8; j++) { srow[t * 8 + j] = run; run += v[j]; }
    if (t == 1023) srow[8192] = run;
}

// scatter sampled edges into slot-grouped sfin
__global__ void k_sscatter(const unsigned long long* __restrict__ slist,
                           const int* __restrict__ scnt, const int* __restrict__ srow,
                           int* __restrict__ sfill, int2* __restrict__ sfin) {
    int i = blockIdx.x * blockDim.x + threadIdx.x;
    if (i >= scnt[0]) return;
    unsigned long long pk = slist[i];
    int s = (int)(pk & 0x3FFFFu);
    int slot = (int)((pk >> 18) & 8191u);
    int vbits = (int)(pk >> 32);
    int pos = srow[slot] + atomicAdd(&sfill[slot], 1);
    sfin[pos] = make_int2(s, vbits);
}

// ---------------- pass B: sort within bucket (LDS hist + scan), emit dense CSR ----------------
// plain tmp loads: each block re-reads its 147 KB bucket twice; it fits L2, NT would evict
__global__ void k_bsort(const int2* __restrict__ tmp, const int* __restrict__ gcur,
                        const int* __restrict__ bucket_ptr, int* __restrict__ row_ptr,
                        int2* __restrict__ fin) {
    __shared__ int cnt[BW + 64];
    __shared__ int off[BW + 64];
    int b = blockIdx.x, t = threadIdx.x;  // 512 threads
    int node0 = b * BW;
    int nodes = min(BW, N_NODES - node0);
    int gbase = bucket_ptr[b];
    int count = gcur[b];
    const int2* tb = tmp + (size_t)b * STRIDE;
    for (int i = t; i < BW + 64; i += 512) cnt[i] = 0;
    __syncthreads();
    for (int e = t; e < count; e += 512) atomicAdd(&cnt[tb[e].x & 1023], 1);
    __syncthreads();
    if (t < 64) {
        int lane = t;
        int carry = 0;
        for (int c = 0; c < 10; c++) {
            int i = c * 64 + lane;
            int x = (i < nodes) ? cnt[i] : 0;
            int incl = x;
            for (int o = 1; o < 64; o <<= 1) {
                int y = __shfl_up(incl, o);
                if (lane >= o) incl += y;
            }
            if (i <= nodes) off[i] = carry + incl - x;
            carry += __shfl(incl, 63);
        }
    }
    __syncthreads();
    for (int i = t; i <= nodes; i += 512)
        if (node0 + i <= N_NODES) row_ptr[node0 + i] = gbase + off[i];
    __syncthreads();
    for (int e = t; e < count; e += 512) {
        int2 r = tb[e];
        int local = r.x & 1023;
        int pos = gbase + atomicAdd(&off[local], 1);
        fin[pos] = make_int2(r.x >> 10, r.y);  // plain store: L2 write-combines 40KB region
    }
}

// ---------------- bf16 SpMM: one wave per dst node, 8 groups x 8 lanes ----------------
// exact R4 body: PLAIN fin loads (each 128B line consumed over 2 iterations -> must stay
// cached) and PLAIN eout store. Measured 77 us / 224 MB FETCH; NT variants regressed.
#define SPMM_EDGE(r)                                                              \
    {                                                                             \
        const uint4 u = *(const uint4*)(ein + (size_t)(r).x * DIM + q * 8);       \
        float v = __int_as_float((r).y);                                          \
        acc[0] += v * blo(u.x); acc[1] += v * bhi(u.x);                           \
        acc[2] += v * blo(u.y); acc[3] += v * bhi(u.y);                           \
        acc[4] += v * blo(u.z); acc[5] += v * bhi(u.z);                           \
        acc[6] += v * blo(u.w); acc[7] += v * bhi(u.w);                           \
    }

__global__ void k_spmm16(const ushort* __restrict__ ein, ushort* __restrict__ eout,
                         const int* __restrict__ row_ptr, const int2* __restrict__ fin) {
    int wave = (blockIdx.x * blockDim.x + threadIdx.x) >> 6;
    if (wave >= N_NODES) return;
    int lane = threadIdx.x & 63;
    int g = lane >> 3;  // edge group 0..7
    int q = lane & 7;   // 8 bf16 dims per lane
    int start = row_ptr[wave], end = row_ptr[wave + 1];
    float acc[8];
#pragma unroll
    for (int j = 0; j < 8; j++) acc[j] = 0.f;
    int e = start + g;
    for (; e + 8 < end; e += 16) {
        int2 r0 = fin[e];
        int2 r1 = fin[e + 8];
        SPMM_EDGE(r0);
        SPMM_EDGE(r1);
    }
    for (; e < end; e += 8) {
        int2 r0 = fin[e];
        SPMM_EDGE(r0);
    }
#pragma unroll
    for (int off = 8; off < 64; off <<= 1) {
#pragma unroll
        for (int j = 0; j < 8; j++) acc[j] += __shfl_xor(acc[j], off);
    }
    if (lane < 8) {
        uint4 p;
        p.x = pack2(acc[0], acc[1]);
        p.y = pack2(acc[2], acc[3]);
        p.z = pack2(acc[4], acc[5]);
        p.w = pack2(acc[6], acc[7]);
        *(uint4*)(eout + (size_t)wave * DIM + q * 8) = p;
    }
}

// layer-3 at sampled slots only -> l3 (overwrite; zero rows for empty slots)
__global__ void k_samp(const ushort* __restrict__ ein, const int* __restrict__ srow,
                       const int2* __restrict__ sfin, float* __restrict__ l3) {
    int slot = (blockIdx.x * blockDim.x + threadIdx.x) >> 6;
    if (slot >= 2 * BATCH) return;
    int lane = threadIdx.x & 63;
    int g = lane >> 3;
    int q = lane & 7;
    int start = srow[slot], end = srow[slot + 1];
    float acc[8];
#pragma unroll
    for (int j = 0; j < 8; j++) acc[j] = 0.f;
    for (int e = start + g; e < end; e += 8) {
        int2 r = sfin[e];
        SPMM_EDGE(r);
    }
#pragma unroll
    for (int off = 8; off < 64; off <<= 1) {
#pragma unroll
        for (int j = 0; j < 8; j++) acc[j] += __shfl_xor(acc[j], off);
    }
    if (lane < 8) {
        float* row = l3 + (size_t)slot * DIM + q * 8;
        *(float4*)row = make_float4(acc[0], acc[1], acc[2], acc[3]);
        *(float4*)(row + 4) = make_float4(acc[4], acc[5], acc[6], acc[7]);
    }
}

// layer-0 + layer-1: acc = fp32 table row + bf16 ebf1 row (fused, overwrite)
__global__ void k_gacc0(const float* __restrict__ uemb, const float* __restrict__ iemb,
                        const ushort* __restrict__ emb, const int* __restrict__ users,
                        const int* __restrict__ items, float* __restrict__ accU,
                        float* __restrict__ accI) {
    int i = blockIdx.x * blockDim.x + threadIdx.x;
    if (i >= 2 * BATCH * DIM) return;
    int j = (i < BATCH * DIM) ? i : i - BATCH * DIM;
    int b = j >> 6, l = j & 63;
    if (i < BATCH * DIM) {
        int n = users[b];
        unsigned int u = emb[(size_t)n * DIM + l];
        accU[j] = uemb[(size_t)n * DIM + l] + __uint_as_float(u << 16);
    } else {
        int n = items[b];
        unsigned int u = emb[(size_t)(n + N_USERS) * DIM + l];
        accI[j] = iemb[(size_t)n * DIM + l] + __uint_as_float(u << 16);
    }
}

// layer-2: accumulate both sample sets from bf16 table
__global__ void k_gacc(const ushort* __restrict__ emb, const int* __restrict__ users,
                       const int* __restrict__ items, float* __restrict__ accU,
                       float* __restrict__ accI) {
    int i = blockIdx.x * blockDim.x + threadIdx.x;
    if (i >= 2 * BATCH * DIM) return;
    int j = (i < BATCH * DIM) ? i : i - BATCH * DIM;
    int b = j >> 6, l = j & 63;
    if (i < BATCH * DIM) {
        unsigned int u = emb[(size_t)users[b] * DIM + l];
        accU[j] += __uint_as_float(u << 16);
    } else {
        unsigned int u = emb[(size_t)(items[b] + N_USERS) * DIM + l];
        accI[j] += __uint_as_float(u << 16);
    }
}

// final dot: (acc + l3[canonical slot]) pairs
__global__ void k_dot(const float* __restrict__ accU, const float* __restrict__ accI,
                      const float* __restrict__ l3, const int* __restrict__ map,
                      const int* __restrict__ users, const int* __restrict__ items,
                      float* __restrict__ out) {
    int b = (blockIdx.x * blockDim.x + threadIdx.x) >> 6;
    if (b >= BATCH) return;
    int lane = threadIdx.x & 63;
    int cu = map[users[b]];
    int ci = map[items[b] + N_USERS];
    float aU = accU[b * 64 + lane] + l3[(size_t)cu * 64 + lane];
    float aI = accI[b * 64 + lane] + l3[(size_t)ci * 64 + lane];
    float p = aU * aI;
    for (int off = 32; off; off >>= 1) p += __shfl_xor(p, off);
    if (lane == 0) out[b] = p * (1.0f / 16.0f);  // (acc/4)·(acc/4)
}

// ---------------- launch ----------------

extern "C" void kernel_launch(void* const* d_in, const int* in_sizes, int n_in,
                              void* d_out, int out_size, void* d_ws, size_t ws_size,
                              hipStream_t stream) {
    const float* user_emb = (const float*)d_in[0];
    const float* item_emb = (const float*)d_in[1];
    const float* vals = (const float*)d_in[2];
    const int* src = (const int*)d_in[3];
    const int* dst = (const int*)d_in[4];
    const int* users = (const int*)d_in[5];
    const int* items = (const int*)d_in[6];
    float* out = (float*)d_out;

    char* ws = (char*)d_ws;
    size_t off = 0;
    auto alloc = [&](size_t bytes) {
        char* p = ws + off;
        off += (bytes + 255) & ~(size_t)255;
        return p;
    };
    ushort* ebf0 = (ushort*)alloc((size_t)N_NODES * DIM * 2);  // 19.2 MB bf16 concat tables
    ushort* ebf1 = (ushort*)alloc((size_t)N_NODES * DIM * 2);  // layer-1 out (aliases tmp lo)
    ushort* ebf2 = (ushort*)alloc((size_t)N_NODES * DIM * 2);  // layer-2 out (aliases tmp hi)
    int2* fin = (int2*)alloc((size_t)N_EDGES * 8);             // 32 MB dense CSR records
    int* row_ptr = (int*)alloc((size_t)(N_NODES + 1) * 4);
    int* bucket_ptr = (int*)alloc((size_t)(NBKT + 1) * 4);
    int* gcur = (int*)alloc((size_t)NBKT * 4);
    int* map = (int*)alloc((size_t)N_NODES * 4);
    int* sdeg = (int*)alloc((size_t)2 * BATCH * 4);
    int* srow = (int*)alloc((size_t)(2 * BATCH + 1) * 4);
    int* sfill = (int*)alloc((size_t)2 * BATCH * 4);
    int* scnt = (int*)alloc(256);
    unsigned long long* slist = (unsigned long long*)alloc((size_t)SLIST_CAP * 8);
    int2* sfin = (int2*)alloc((size_t)SLIST_CAP * 8);
    float* l3 = (float*)alloc((size_t)2 * BATCH * DIM * 4);
    float* accU = (float*)alloc((size_t)BATCH * DIM * 4);
    float* accI = (float*)alloc((size_t)BATCH * DIM * 4);
    // 37.75 MB fixed-stride partition scratch aliases ebf1+ebf2 (38.4 MB contiguous);
    // tmp is dead after k_bsort, before ebf1/2 are first written.
    int2* tmp = (int2*)ebf1;

    hipMemsetAsync(map, 0xFF, (size_t)N_NODES * 4, stream);  // map = -1

    k_markcvt<<<(N_NODES * DIM / 4 + 255) / 256, 256, 0, stream>>>(
        user_emb, item_emb, ebf0, users, items, map, sdeg, sfill, gcur, scnt);

    int pa_blocks = (N_EDGES + PA_EDGES - 1) / PA_EDGES;
    k_partition<<<pa_blocks, 256, 0, stream>>>(src, dst, vals, map, gcur, tmp, sdeg, scnt, slist);
    k_scan2<<<2, 1024, 0, stream>>>(gcur, bucket_ptr, sdeg, srow);
    k_sscatter<<<SLIST_CAP / 256, 256, 0, stream>>>(slist, scnt, srow, sfill, sfin);
    k_bsort<<<NBKT, 512, 0, stream>>>(tmp, gcur, bucket_ptr, row_ptr, fin);

    int gb = (2 * BATCH * DIM + 255) / 256;
    int spmm_blocks = (N_NODES * 64 + 255) / 256;
    // layer 1: ebf0 -> ebf1, then fused layer-0 + layer-1 sampled accumulate
    k_spmm16<<<spmm_blocks, 256, 0, stream>>>(ebf0, ebf1, row_ptr, fin);
    k_gacc0<<<gb, 256, 0, stream>>>(user_emb, item_emb, ebf1, users, items, accU, accI);
    // layer 2: ebf1 -> ebf2
    k_spmm16<<<spmm_blocks, 256, 0, stream>>>(ebf1, ebf2, row_ptr, fin);
    k_gacc<<<gb, 256, 0, stream>>>(ebf2, users, items, accU, accI);
    // layer 3: sampled rows only -> l3
    k_samp<<<(2 * BATCH * 64 + 255) / 256, 256, 0, stream>>>(ebf2, srow, sfin, l3);

    k_dot<<<(BATCH * 64 + 255) / 256, 256, 0, stream>>>(accU, accI, l3, map, users, items, out);
}

// Round 10
// 397.858 us; speedup vs baseline: 7.2074x; 1.0578x over previous
//
#include <hip/hip_runtime.h>
#include <hip/hip_bf16.h>

#define N_USERS 100000
#define N_ITEMS 50000
#define N_NODES 150000
#define DIM 64
#define N_EDGES 4000000
#define BATCH 4096

#define NBKT 512
#define BW 294           // nodes per bucket; 512*294 = 150528 >= 150000
#define STRIDE 9216      // tmp records per bucket (mean 7840, sigma ~88 -> +15.6 sigma)
#define PA_EDGES 4096    // edges per partition block
#define PA_ITER 16       // edges per thread (register-cached)
#define SCAP 384         // sampled-edge staging slots per partition block (mean ~217)
#define SLIST_CAP 262144

// ---------------- bf16 helpers ----------------
__device__ __forceinline__ float blo(unsigned int u) { return __uint_as_float(u << 16); }
__device__ __forceinline__ float bhi(unsigned int u) { return __uint_as_float(u & 0xffff0000u); }
__device__ __forceinline__ unsigned int f2b(float f) {  // RTNE
    unsigned int x = __float_as_uint(f);
    return (x + 0x7fffu + ((x >> 16) & 1u)) >> 16;
}
__device__ __forceinline__ unsigned int pack2(float a, float b) {
    return f2b(a) | (f2b(b) << 16);
}

// fp32 tables -> bf16 concat table, fused with sampled-node marking + counter init
__global__ void k_markcvt(const float* __restrict__ uemb, const float* __restrict__ iemb,
                          ushort* __restrict__ out, const int* __restrict__ users,
                          const int* __restrict__ items, int* __restrict__ map,
                          int* __restrict__ sdeg, int* __restrict__ sfill,
                          int* __restrict__ gcur, int* __restrict__ scnt) {
    int tid = blockIdx.x * blockDim.x + threadIdx.x;
    if (tid < 2 * BATCH) {
        sdeg[tid] = 0;
        sfill[tid] = 0;
        if (tid < NBKT) gcur[tid] = 0;
        if (tid == 0) scnt[0] = 0;
        if (tid < BATCH) map[users[tid]] = tid;          // dup race: any winner is canonical
        else map[items[tid - BATCH] + N_USERS] = tid;    // tid = BATCH + b
    }
    int i = tid * 4;
    if (i >= N_NODES * DIM) return;
    const float* srcp = (i < N_USERS * DIM) ? (uemb + i) : (iemb + (i - N_USERS * DIM));
    float4 v;
    v.x = __builtin_nontemporal_load(srcp + 0);
    v.y = __builtin_nontemporal_load(srcp + 1);
    v.z = __builtin_nontemporal_load(srcp + 2);
    v.w = __builtin_nontemporal_load(srcp + 3);
    *(uint2*)(out + i) = make_uint2(pack2(v.x, v.y), pack2(v.z, v.w));
}

// ---------------- two-pass register-cached partition + sampled-edge filter ----------------
// pass 1: edges -> registers, LDS histogram; reserve per-bin global runs; pass 2: scatter
// from registers into reserved runs (per-block ~128B runs per bin -> L2 write-combines).
__global__ void __launch_bounds__(256, 4) k_partition(
        const int* __restrict__ src, const int* __restrict__ dst,
        const float* __restrict__ vals, const int* __restrict__ map,
        int* __restrict__ gcur, int2* __restrict__ tmp,
        int* __restrict__ sdeg, int* __restrict__ scnt,
        unsigned long long* __restrict__ slist) {
    __shared__ int cnt[NBKT];     // pass-1 histogram, then reused as pass-2 cursor
    __shared__ int base_s[NBKT];  // reserved global run base per bin
    __shared__ unsigned long long sbuf[SCAP];  // sampled-edge staging
    __shared__ int scnt_s, sbase_s;
    int t = threadIdx.x;
    for (int i = t; i < NBKT; i += 256) cnt[i] = 0;
    if (t == 0) scnt_s = 0;
    __syncthreads();
    size_t base = (size_t)blockIdx.x * PA_EDGES;
    int myb[PA_ITER];
    int mykey[PA_ITER];
    int myval[PA_ITER];
#pragma unroll
    for (int it = 0; it < PA_ITER; it++) {
        size_t i = base + (size_t)it * 256 + t;
        myb[it] = -1;
        if (i < N_EDGES) {
            int d = __builtin_nontemporal_load(dst + i);
            int s = __builtin_nontemporal_load(src + i);
            float v = __builtin_nontemporal_load(vals + i);
            int b = d / BW;
            int local = d - b * BW;
            myb[it] = b;
            mykey[it] = (s << 9) | local;
            myval[it] = __float_as_int(v);
            atomicAdd(&cnt[b], 1);
            int ms = map[d];
            if (ms >= 0) {  // edge feeds a sampled node's layer-3 row
                atomicAdd(&sdeg[ms], 1);
                unsigned long long pk = ((unsigned long long)(unsigned int)__float_as_int(v) << 32) |
                                        ((unsigned int)ms << 18) | (unsigned int)s;
                int sl = atomicAdd(&scnt_s, 1);
                if (sl < SCAP) sbuf[sl] = pk;
                else slist[atomicAdd(scnt, 1)] = pk;  // very rare
            }
        }
    }
    __syncthreads();
    // reserve global runs (one atomic per non-empty bin)
    for (int i = t; i < NBKT; i += 256) {
        int c = cnt[i];
        base_s[i] = (c > 0) ? atomicAdd(&gcur[i], c) : 0;
    }
    if (t == 0) {
        int c = min(scnt_s, SCAP);
        sbase_s = (c > 0) ? atomicAdd(scnt, c) : 0;
    }
    __syncthreads();
    for (int i = t; i < NBKT; i += 256) cnt[i] = 0;  // reuse as cursor
    __syncthreads();
    // drain sampled staging (coalesced)
    int stot = min(scnt_s, SCAP);
    for (int i = t; i < stot; i += 256) slist[sbase_s + i] = sbuf[i];
    // pass 2: scatter records from registers into reserved runs
#pragma unroll
    for (int it = 0; it < PA_ITER; it++) {
        int b = myb[it];
        if (b >= 0) {
            int pos = base_s[b] + atomicAdd(&cnt[b], 1);
            tmp[(size_t)b * STRIDE + pos] = make_int2(mykey[it], myval[it]);
        }
    }
}

// fused scans: block 0 = bucket scan (gcur -> bucket_ptr), block 1 = sampled scan (sdeg -> srow)
__global__ void k_scan2(const int* __restrict__ gcur, int* __restrict__ bucket_ptr,
                        const int* __restrict__ sdeg, int* __restrict__ srow) {
    __shared__ int ws[16];
    int t = threadIdx.x;  // 1024
    if (blockIdx.x == 0) {
        if (t >= 64) return;
        int lane = t;
        int carry = 0;
        for (int c = 0; c < NBKT / 64; c++) {
            int i = c * 64 + lane;
            int x = gcur[i];
            int incl = x;
            for (int off = 1; off < 64; off <<= 1) {
                int y = __shfl_up(incl, off);
                if (lane >= off) incl += y;
            }
            bucket_ptr[i] = carry + incl - x;
            carry += __shfl(incl, 63);
        }
        if (lane == 0) bucket_ptr[NBKT] = N_EDGES;
        return;
    }
    int v[8], p = 0;
#pragma unroll
    for (int j = 0; j < 8; j++) { v[j] = sdeg[t * 8 + j]; p += v[j]; }
    int lane = t & 63, w = t >> 6;
    int incl = p;
    for (int o = 1; o < 64; o <<= 1) {
        int y = __shfl_up(incl, o);
        if (lane >= o) incl += y;
    }
    if (lane == 63) ws[w] = incl;
    __syncthreads();
    int woff = 0;
    for (int j = 0; j < w; j++) woff += ws[j];
    int run = woff + incl - p;
#pragma unroll
    for (int j = 0; j < 8; j++) { srow[t * 8 + j] = run; run += v[j]; }
    if (t == 1023) srow[8192] = run;
}

// scatter sampled edges into slot-grouped sfin
__global__ void k_sscatter(const unsigned long long* __restrict__ slist,
                           const int* __restrict__ scnt, const int* __restrict__ srow,
                           int* __restrict__ sfill, int2* __restrict__ sfin) {
    int i = blockIdx.x * blockDim.x + threadIdx.x;
    if (i >= scnt[0]) return;
    unsigned long long pk = slist[i];
    int s = (int)(pk & 0x3FFFFu);
    int slot = (int)((pk >> 18) & 8191u);
    int vbits = (int)(pk >> 32);
    int pos = srow[slot] + atomicAdd(&sfill[slot], 1);
    sfin[pos] = make_int2(s, vbits);
}

// ---------------- pass B: sort within bucket (LDS hist + scan), emit dense CSR ----------------
// plain tmp loads: each block re-reads its ~74 KB bucket twice; it fits L2, NT would evict
__global__ void k_bsort(const int2* __restrict__ tmp, const int* __restrict__ gcur,
                        const int* __restrict__ bucket_ptr, int* __restrict__ row_ptr,
                        int2* __restrict__ fin) {
    __shared__ int cnt[BW + 64];
    __shared__ int off[BW + 64];
    int b = blockIdx.x, t = threadIdx.x;  // 512 threads
    int node0 = b * BW;
    int nodes = min(BW, N_NODES - node0);  // may be negative for trailing empty buckets
    int gbase = bucket_ptr[b];
    int count = gcur[b];
    const int2* tb = tmp + (size_t)b * STRIDE;
    for (int i = t; i < BW + 64; i += 512) cnt[i] = 0;
    __syncthreads();
    for (int e = t; e < count; e += 512) atomicAdd(&cnt[tb[e].x & 511], 1);
    __syncthreads();
    if (t < 64) {
        int lane = t;
        int carry = 0;
        for (int c = 0; c < 5; c++) {
            int i = c * 64 + lane;
            int x = (i < nodes) ? cnt[i] : 0;
            int incl = x;
            for (int o = 1; o < 64; o <<= 1) {
                int y = __shfl_up(incl, o);
                if (lane >= o) incl += y;
            }
            if (i <= nodes) off[i] = carry + incl - x;
            carry += __shfl(incl, 63);
        }
    }
    __syncthreads();
    for (int i = t; i <= nodes; i += 512)
        if (node0 + i <= N_NODES) row_ptr[node0 + i] = gbase + off[i];
    __syncthreads();
    for (int e = t; e < count; e += 512) {
        int2 r = tb[e];
        int local = r.x & 511;
        int pos = gbase + atomicAdd(&off[local], 1);
        fin[pos] = make_int2(r.x >> 9, r.y);  // plain store: L2 write-combines the region
    }
}

// ---------------- bf16 SpMM: one wave per dst node, 8 groups x 8 lanes ----------------
// PLAIN fin loads (each 128B line consumed over 2 iterations -> must stay cached) and
// PLAIN eout store. Measured 77 us / 224 MB FETCH; NT variants regressed (R7/R8).
#define SPMM_EDGE(r)                                                              \
    {                                                                             \
        const uint4 u = *(const uint4*)(ein + (size_t)(r).x * DIM + q * 8);       \
        float v = __int_as_float((r).y);                                          \
        acc[0] += v * blo(u.x); acc[1] += v * bhi(u.x);                           \
        acc[2] += v * blo(u.y); acc[3] += v * bhi(u.y);                           \
        acc[4] += v * blo(u.z); acc[5] += v * bhi(u.z);                           \
        acc[6] += v * blo(u.w); acc[7] += v * bhi(u.w);                           \
    }

__global__ void k_spmm16(const ushort* __restrict__ ein, ushort* __restrict__ eout,
                         const int* __restrict__ row_ptr, const int2* __restrict__ fin) {
    int wave = (blockIdx.x * blockDim.x + threadIdx.x) >> 6;
    if (wave >= N_NODES) return;
    int lane = threadIdx.x & 63;
    int g = lane >> 3;  // edge group 0..7
    int q = lane & 7;   // 8 bf16 dims per lane
    int start = row_ptr[wave], end = row_ptr[wave + 1];
    float acc[8];
#pragma unroll
    for (int j = 0; j < 8; j++) acc[j] = 0.f;
    int e = start + g;
    for (; e + 8 < end; e += 16) {
        int2 r0 = fin[e];
        int2 r1 = fin[e + 8];
        SPMM_EDGE(r0);
        SPMM_EDGE(r1);
    }
    for (; e < end; e += 8) {
        int2 r0 = fin[e];
        SPMM_EDGE(r0);
    }
#pragma unroll
    for (int off = 8; off < 64; off <<= 1) {
#pragma unroll
        for (int j = 0; j < 8; j++) acc[j] += __shfl_xor(acc[j], off);
    }
    if (lane < 8) {
        uint4 p;
        p.x = pack2(acc[0], acc[1]);
        p.y = pack2(acc[2], acc[3]);
        p.z = pack2(acc[4], acc[5]);
        p.w = pack2(acc[6], acc[7]);
        *(uint4*)(eout + (size_t)wave * DIM + q * 8) = p;
    }
}

// layer-3 at sampled slots only -> l3 (overwrite; zero rows for empty slots)
__global__ void k_samp(const ushort* __restrict__ ein, const int* __restrict__ srow,
                       const int2* __restrict__ sfin, float* __restrict__ l3) {
    int slot = (blockIdx.x * blockDim.x + threadIdx.x) >> 6;
    if (slot >= 2 * BATCH) return;
    int lane = threadIdx.x & 63;
    int g = lane >> 3;
    int q = lane & 7;
    int start = srow[slot], end = srow[slot + 1];
    float acc[8];
#pragma unroll
    for (int j = 0; j < 8; j++) acc[j] = 0.f;
    for (int e = start + g; e < end; e += 8) {
        int2 r = sfin[e];
        SPMM_EDGE(r);
    }
#pragma unroll
    for (int off = 8; off < 64; off <<= 1) {
#pragma unroll
        for (int j = 0; j < 8; j++) acc[j] += __shfl_xor(acc[j], off);
    }
    if (lane < 8) {
        float* row = l3 + (size_t)slot * DIM + q * 8;
        *(float4*)row = make_float4(acc[0], acc[1], acc[2], acc[3]);
        *(float4*)(row + 4) = make_float4(acc[4], acc[5], acc[6], acc[7]);
    }
}

// layer-0 + layer-1: acc = fp32 table row + bf16 ebf1 row (fused, overwrite)
__global__ void k_gacc0(const float* __restrict__ uemb, const float* __restrict__ iemb,
                        const ushort* __restrict__ emb, const int* __restrict__ users,
                        const int* __restrict__ items, float* __restrict__ accU,
                        float* __restrict__ accI) {
    int i = blockIdx.x * blockDim.x + threadIdx.x;
    if (i >= 2 * BATCH * DIM) return;
    int j = (i < BATCH * DIM) ? i : i - BATCH * DIM;
    int b = j >> 6, l = j & 63;
    if (i < BATCH * DIM) {
        int n = users[b];
        unsigned int u = emb[(size_t)n * DIM + l];
        accU[j] = uemb[(size_t)n * DIM + l] + __uint_as_float(u << 16);
    } else {
        int n = items[b];
        unsigned int u = emb[(size_t)(n + N_USERS) * DIM + l];
        accI[j] = iemb[(size_t)n * DIM + l] + __uint_as_float(u << 16);
    }
}

// layer-2: accumulate both sample sets from bf16 table
__global__ void k_gacc(const ushort* __restrict__ emb, const int* __restrict__ users,
                       const int* __restrict__ items, float* __restrict__ accU,
                       float* __restrict__ accI) {
    int i = blockIdx.x * blockDim.x + threadIdx.x;
    if (i >= 2 * BATCH * DIM) return;
    int j = (i < BATCH * DIM) ? i : i - BATCH * DIM;
    int b = j >> 6, l = j & 63;
    if (i < BATCH * DIM) {
        unsigned int u = emb[(size_t)users[b] * DIM + l];
        accU[j] += __uint_as_float(u << 16);
    } else {
        unsigned int u = emb[(size_t)(items[b] + N_USERS) * DIM + l];
        accI[j] += __uint_as_float(u << 16);
    }
}

// final dot: (acc + l3[canonical slot]) pairs
__global__ void k_dot(const float* __restrict__ accU, const float* __restrict__ accI,
                      const float* __restrict__ l3, const int* __restrict__ map,
                      const int* __restrict__ users, const int* __restrict__ items,
                      float* __restrict__ out) {
    int b = (blockIdx.x * blockDim.x + threadIdx.x) >> 6;
    if (b >= BATCH) return;
    int lane = threadIdx.x & 63;
    int cu = map[users[b]];
    int ci = map[items[b] + N_USERS];
    float aU = accU[b * 64 + lane] + l3[(size_t)cu * 64 + lane];
    float aI = accI[b * 64 + lane] + l3[(size_t)ci * 64 + lane];
    float p = aU * aI;
    for (int off = 32; off; off >>= 1) p += __shfl_xor(p, off);
    if (lane == 0) out[b] = p * (1.0f / 16.0f);  // (acc/4)·(acc/4)
}

// ---------------- launch ----------------

extern "C" void kernel_launch(void* const* d_in, const int* in_sizes, int n_in,
                              void* d_out, int out_size, void* d_ws, size_t ws_size,
                              hipStream_t stream) {
    const float* user_emb = (const float*)d_in[0];
    const float* item_emb = (const float*)d_in[1];
    const float* vals = (const float*)d_in[2];
    const int* src = (const int*)d_in[3];
    const int* dst = (const int*)d_in[4];
    const int* users = (const int*)d_in[5];
    const int* items = (const int*)d_in[6];
    float* out = (float*)d_out;

    char* ws = (char*)d_ws;
    size_t off = 0;
    auto alloc = [&](size_t bytes) {
        char* p = ws + off;
        off += (bytes + 255) & ~(size_t)255;
        return p;
    };
    ushort* ebf0 = (ushort*)alloc((size_t)N_NODES * DIM * 2);  // 19.2 MB bf16 concat tables
    ushort* ebf1 = (ushort*)alloc((size_t)N_NODES * DIM * 2);  // layer-1 out (aliases tmp lo)
    ushort* ebf2 = (ushort*)alloc((size_t)N_NODES * DIM * 2);  // layer-2 out (aliases tmp hi)
    int2* fin = (int2*)alloc((size_t)N_EDGES * 8);             // 32 MB dense CSR records
    int* row_ptr = (int*)alloc((size_t)(N_NODES + 1) * 4);
    int* bucket_ptr = (int*)alloc((size_t)(NBKT + 1) * 4);
    int* gcur = (int*)alloc((size_t)NBKT * 4);
    int* map = (int*)alloc((size_t)N_NODES * 4);
    int* sdeg = (int*)alloc((size_t)2 * BATCH * 4);
    int* srow = (int*)alloc((size_t)(2 * BATCH + 1) * 4);
    int* sfill = (int*)alloc((size_t)2 * BATCH * 4);
    int* scnt = (int*)alloc(256);
    unsigned long long* slist = (unsigned long long*)alloc((size_t)SLIST_CAP * 8);
    int2* sfin = (int2*)alloc((size_t)SLIST_CAP * 8);
    float* l3 = (float*)alloc((size_t)2 * BATCH * DIM * 4);
    float* accU = (float*)alloc((size_t)BATCH * DIM * 4);
    float* accI = (float*)alloc((size_t)BATCH * DIM * 4);
    // 37.75 MB fixed-stride partition scratch aliases ebf1+ebf2 (38.4 MB contiguous);
    // tmp is dead after k_bsort, before ebf1/2 are first written.
    int2* tmp = (int2*)ebf1;

    hipMemsetAsync(map, 0xFF, (size_t)N_NODES * 4, stream);  // map = -1

    k_markcvt<<<(N_NODES * DIM / 4 + 255) / 256, 256, 0, stream>>>(
        user_emb, item_emb, ebf0, users, items, map, sdeg, sfill, gcur, scnt);

    int pa_blocks = (N_EDGES + PA_EDGES - 1) / PA_EDGES;
    k_partition<<<pa_blocks, 256, 0, stream>>>(src, dst, vals, map, gcur, tmp, sdeg, scnt, slist);
    k_scan2<<<2, 1024, 0, stream>>>(gcur, bucket_ptr, sdeg, srow);
    k_sscatter<<<SLIST_CAP / 256, 256, 0, stream>>>(slist, scnt, srow, sfill, sfin);
    k_bsort<<<NBKT, 512, 0, stream>>>(tmp, gcur, bucket_ptr, row_ptr, fin);

    int gb = (2 * BATCH * DIM + 255) / 256;
    int spmm_blocks = (N_NODES * 64 + 255) / 256;
    // layer 1: ebf0 -> ebf1, then fused layer-0 + layer-1 sampled accumulate
    k_spmm16<<<spmm_blocks, 256, 0, stream>>>(ebf0, ebf1, row_ptr, fin);
    k_gacc0<<<gb, 256, 0, stream>>>(user_emb, item_emb, ebf1, users, items, accU, accI);
    // layer 2: ebf1 -> ebf2
    k_spmm16<<<spmm_blocks, 256, 0, stream>>>(ebf1, ebf2, row_ptr, fin);
    k_gacc<<<gb, 256, 0, stream>>>(ebf2, users, items, accU, accI);
    // layer 3: sampled rows only -> l3
    k_samp<<<(2 * BATCH * 64 + 255) / 256, 256, 0, stream>>>(ebf2, srow, sfin, l3);

    k_dot<<<(BATCH * 64 + 255) / 256, 256, 0, stream>>>(accU, accI, l3, map, users, items, out);
}